// Round 5
// baseline (102.863 us; speedup 1.0000x reference)
//
#include <hip/hip_runtime.h>
#include <cmath>

// Problem constants
#define BB 4
#define NN 1024
#define DD 512
#define HH 8
#define HDIM 64
#define ROWS (BB * NN)      // 4096
#define NCHUNK 16
// Split-bf16 3-product GEMM: logical K = 1536 = [Ahi|Ahi|Alo] x [Whi|Wlo|Whi].
// STORAGE is compact [hi|lo] (1024 cols); stage() remaps per K-segment.
#define KSTORE 1024
#define WMAT2 ((size_t)512 * KSTORE)   // one weight matrix, elems
#define PLANE ((size_t)ROWS * DD)

typedef __bf16 bf16;
typedef bf16  bf16x8 __attribute__((ext_vector_type(8)));
typedef bf16  bf16x4 __attribute__((ext_vector_type(4)));
typedef float f32x4  __attribute__((ext_vector_type(4)));

#define GLOAD_LDS16(g, l) \
    __builtin_amdgcn_global_load_lds((const __attribute__((address_space(1))) void*)(g), \
                                     (__attribute__((address_space(3))) void*)(l), 16, 0, 0)

// ---------------------------------------------------------------------------
// Fused split: x (2048 blocks) and the 4 weight matrices (1024 blocks)
// -> compact [hi(512) | lo(512)] bf16 rows.
// ---------------------------------------------------------------------------
__global__ __launch_bounds__(256)
void split_all(const float* __restrict__ x,
               const float* __restrict__ Wq, const float* __restrict__ Wk,
               const float* __restrict__ Wv, const float* __restrict__ Wo,
               bf16* __restrict__ xa, bf16* __restrict__ wa)
{
    const int bid = blockIdx.x;
    const float* src;
    bf16* dstbase;
    int t;
    if (bid < 2048) {                       // x: 2M floats
        t = bid * 256 + threadIdx.x;
        src = x;
        dstbase = xa;
    } else {                                // weights: 4 x 256K floats
        int wb = bid - 2048;
        int m  = wb >> 8;                   // 256 blocks per matrix
        t = (wb & 255) * 256 + threadIdx.x;
        src = (m == 0) ? Wq : (m == 1) ? Wk : (m == 2) ? Wv : Wo;
        dstbase = wa + (size_t)m * WMAT2;
    }
    float4 v = ((const float4*)src)[t];
    float a[4] = {v.x, v.y, v.z, v.w};
    int r = t >> 7;                         // 128 float4 per 512-col row
    int c = (t & 127) * 4;
    bf16x4 hi, lo;
    #pragma unroll
    for (int i = 0; i < 4; ++i) {
        bf16 h = (bf16)a[i];
        hi[i] = h;
        lo[i] = (bf16)(a[i] - (float)h);
    }
    bf16* dst = dstbase + (size_t)r * KSTORE + c;
    *(bf16x4*)(dst)       = hi;
    *(bf16x4*)(dst + 512) = lo;
}

// ---------------------------------------------------------------------------
// MFMA GEMM, double-buffered LDS + prefetch, read-side XOR swizzle, compact
// [hi|lo] storage with per-K-segment remap.
// OUTMODE 0: BM=BN=128, wave tile 64x64, grid (32,4,3): z = matrix (q,k,v);
//            elu + per-head L2norm for z<2; write (B,H,N,64) f32 planes.
// OUTMODE 1: BM=BN=64, wave tile 32x32, grid (64,8): plain store + bias.
// ---------------------------------------------------------------------------
template<int OUTMODE>
__global__ __launch_bounds__(256)
void mm_aug(const bf16* __restrict__ A, const bf16* __restrict__ Wbase,
            const float* __restrict__ b0, const float* __restrict__ b1,
            const float* __restrict__ b2, float* __restrict__ obase)
{
    constexpr int BM = (OUTMODE == 0) ? 128 : 64;
    constexpr int BN = (OUTMODE == 0) ? 128 : 64;
    constexpr int MI = BM / 32;               // M-frags per wave (4 or 2)
    constexpr int NW = BN / 32;               // N-frags per wave (4 or 2)

    __shared__ __align__(16) bf16 As[2][BM * 64];
    __shared__ __align__(16) bf16 Bs[2][BN * 64];

    const int t    = threadIdx.x;
    const int lane = t & 63;
    const int wid  = t >> 6;
    const int wr   = wid >> 1;
    const int wc   = wid & 1;
    const int l16  = lane & 15;
    const int g16  = lane >> 4;

    const int r0 = blockIdx.x * BM;
    const int c0 = blockIdx.y * BN;
    const int z  = (OUTMODE == 0) ? blockIdx.z : 0;

    const bf16* Wm = (OUTMODE == 0) ? Wbase + (size_t)z * WMAT2 : Wbase;

    auto stage = [&](int buf, int kt) {
        const int k0   = kt * 64;
        // A segments: [hi, hi, lo] ; W segments: [Whi, Wlo, Whi]
        const int aoff = (k0 < 1024) ? (k0 & 511) : (k0 - 512);
        const int woff = (k0 < 1024) ? k0 : (k0 - 1024);
        #pragma unroll
        for (int i = 0; i < BM / 32; ++i) {
            int f = i * 256 + t;
            int r = f >> 3;
            int sc = (f & 7) ^ (r & 7);
            GLOAD_LDS16(A + (size_t)(r0 + r) * KSTORE + aoff + sc * 8,
                        &As[buf][(i * 256 + wid * 64) * 8]);
        }
        #pragma unroll
        for (int i = 0; i < BN / 32; ++i) {
            int f = i * 256 + t;
            int r = f >> 3;
            int sc = (f & 7) ^ (r & 7);
            GLOAD_LDS16(Wm + (size_t)(c0 + r) * KSTORE + woff + sc * 8,
                        &Bs[buf][(i * 256 + wid * 64) * 8]);
        }
    };

    f32x4 acc[MI][NW] = {};

    int cur = 0;
    stage(0, 0);
    __syncthreads();

    for (int kt = 0; kt < 24; ++kt) {
        if (kt + 1 < 24) stage(cur ^ 1, kt + 1);

        bf16x8 af[MI][2], bfr[NW][2];
        #pragma unroll
        for (int mi = 0; mi < MI; ++mi)
            #pragma unroll
            for (int kk = 0; kk < 2; ++kk) {
                int lr = wr * (BM / 2) + mi * 16 + l16;
                int c  = kk * 4 + g16;
                af[mi][kk] = *(const bf16x8*)(&As[cur][lr * 64 + ((c ^ (lr & 7)) * 8)]);
            }
        #pragma unroll
        for (int ni = 0; ni < NW; ++ni)
            #pragma unroll
            for (int kk = 0; kk < 2; ++kk) {
                int lr = wc * (BN / 2) + ni * 16 + l16;
                int c  = kk * 4 + g16;
                bfr[ni][kk] = *(const bf16x8*)(&Bs[cur][lr * 64 + ((c ^ (lr & 7)) * 8)]);
            }
        #pragma unroll
        for (int kk = 0; kk < 2; ++kk)
            #pragma unroll
            for (int mi = 0; mi < MI; ++mi)
                #pragma unroll
                for (int ni = 0; ni < NW; ++ni)
                    acc[mi][ni] = __builtin_amdgcn_mfma_f32_16x16x32_bf16(af[mi][kk], bfr[ni][kk], acc[mi][ni], 0, 0, 0);
        __syncthreads();
        cur ^= 1;
    }

    if (OUTMODE == 1) {
        #pragma unroll
        for (int mi = 0; mi < MI; ++mi)
            #pragma unroll
            for (int ni = 0; ni < NW; ++ni) {
                int cg = c0 + wc * (BN / 2) + ni * 16 + l16;
                float bv = b0[cg];
                #pragma unroll
                for (int r = 0; r < 4; ++r) {
                    int rg = r0 + wr * (BM / 2) + mi * 16 + g16 * 4 + r;
                    obase[(size_t)rg * DD + cg] = acc[mi][ni][r] + bv;
                }
            }
    } else {
        const float* bias = (z == 0) ? b0 : (z == 1) ? b1 : b2;
        float* outp = obase + (size_t)z * PLANE;

        #pragma unroll
        for (int mi = 0; mi < MI; ++mi)
            #pragma unroll
            for (int ni = 0; ni < NW; ++ni) {
                float bv = bias[c0 + wc * 64 + ni * 16 + l16];
                #pragma unroll
                for (int r = 0; r < 4; ++r) {
                    float v = acc[mi][ni][r] + bv;
                    if (z < 2) v = (v > 0.f) ? v : expm1f(v);
                    acc[mi][ni][r] = v;
                }
            }
        if (z < 2) {
            // per-(row, head) L2 norm; wave's 64 cols == one head
            #pragma unroll
            for (int mi = 0; mi < MI; ++mi)
                #pragma unroll
                for (int r = 0; r < 4; ++r) {
                    float ss = 0.f;
                    #pragma unroll
                    for (int ni = 0; ni < NW; ++ni) ss += acc[mi][ni][r] * acc[mi][ni][r];
                    ss += __shfl_xor(ss, 1);
                    ss += __shfl_xor(ss, 2);
                    ss += __shfl_xor(ss, 4);
                    ss += __shfl_xor(ss, 8);
                    float sc = 1.f / fmaxf(sqrtf(ss), 1e-12f);
                    #pragma unroll
                    for (int ni = 0; ni < NW; ++ni) acc[mi][ni][r] *= sc;
                }
        }
        const int h = (c0 >> 6) + wc;
        #pragma unroll
        for (int mi = 0; mi < MI; ++mi)
            #pragma unroll
            for (int r = 0; r < 4; ++r) {
                int rg = r0 + wr * (BM / 2) + mi * 16 + g16 * 4 + r;
                int b = rg >> 10, n = rg & 1023;
                float* dst = outp + ((size_t)(b * HH + h) * NN + n) * HDIM;
                #pragma unroll
                for (int ni = 0; ni < NW; ++ni) dst[ni * 16 + l16] = acc[mi][ni][r];
            }
    }
}

// ---------------------------------------------------------------------------
// Per-chunk state: S_c[d][e] = sum_{n in chunk} K[n][d] * V[n][e]   (64x64)
// ---------------------------------------------------------------------------
__global__ __launch_bounds__(256)
void chunk_state(const float* __restrict__ kb, const float* __restrict__ vb,
                 float* __restrict__ S)
{
    __shared__ float Ks[64 * 64];
    __shared__ float Vs[64 * 64];

    const int bh = blockIdx.x;
    const int ch = blockIdx.y;
    const int t  = threadIdx.x;

    const float4* kg4 = (const float4*)(kb + ((size_t)bh * NN + ch * 64) * HDIM);
    const float4* vg4 = (const float4*)(vb + ((size_t)bh * NN + ch * 64) * HDIM);

    #pragma unroll
    for (int i = 0; i < 4; ++i) {
        int f4 = t + i * 256;
        ((float4*)Ks)[f4] = kg4[f4];
        ((float4*)Vs)[f4] = vg4[f4];
    }
    __syncthreads();

    const int d0 = (t >> 4) * 4;
    const int e0 = (t & 15) * 4;
    f32x4 acc[4] = {};
    for (int n = 0; n < 64; ++n) {
        f32x4 kv = *(const f32x4*)(Ks + n * 64 + d0);
        f32x4 vv = *(const f32x4*)(Vs + n * 64 + e0);
        #pragma unroll
        for (int di = 0; di < 4; ++di) acc[di] += kv[di] * vv;
    }
    float* sg = S + ((size_t)bh * NCHUNK + ch) * 4096;
    #pragma unroll
    for (int di = 0; di < 4; ++di)
        *(f32x4*)(sg + (d0 + di) * 64 + e0) = acc[di];
}

// ---------------------------------------------------------------------------
// Chunk attention: O = Q @ P + tril(Q K^T) @ V -> compact split-bf16 rows.
// P (exclusive prefix of states) is accumulated per-thread in registers from
// the raw states (replaces the separate prefix_scan kernel).
// ---------------------------------------------------------------------------
__global__ __launch_bounds__(256)
void attn_chunk(const float* __restrict__ qb, const float* __restrict__ kb,
                const float* __restrict__ vb, const float* __restrict__ S,
                bf16* __restrict__ aug)
{
    __shared__ float Qs[64][68];   // [i][d], rows 16B-aligned
    __shared__ float Kt[64][68];   // [d][j]
    __shared__ float PA[64 * 68];  // P [d*64+e] first, then scores [i*68+j]
    __shared__ float Vs[64 * 64];

    const int bh = blockIdx.x;
    const int ch = blockIdx.y;
    const int t  = threadIdx.x;

    const float4* qg4 = (const float4*)(qb + ((size_t)bh * NN + ch * 64) * HDIM);
    const float4* kg4 = (const float4*)(kb + ((size_t)bh * NN + ch * 64) * HDIM);
    const float4* vg4 = (const float4*)(vb + ((size_t)bh * NN + ch * 64) * HDIM);
    const float*  stb = S + (size_t)bh * NCHUNK * 4096;

    #pragma unroll
    for (int i = 0; i < 4; ++i) {
        int f4 = t + i * 256;
        int n  = f4 >> 4;
        int d4 = (f4 & 15) * 4;
        float4 q4 = qg4[f4];
        Qs[n][d4 + 0] = q4.x; Qs[n][d4 + 1] = q4.y; Qs[n][d4 + 2] = q4.z; Qs[n][d4 + 3] = q4.w;
        float4 k4 = kg4[f4];
        Kt[d4 + 0][n] = k4.x; Kt[d4 + 1][n] = k4.y; Kt[d4 + 2][n] = k4.z; Kt[d4 + 3][n] = k4.w;
        ((float4*)Vs)[f4] = vg4[f4];
    }

    // exclusive prefix of chunk states, accumulated in regs (L2-resident reads)
    f32x4 racc[4] = {};
    for (int c = 0; c < ch; ++c) {
        const f32x4* sg4 = (const f32x4*)(stb + (size_t)c * 4096);
        #pragma unroll
        for (int i = 0; i < 4; ++i) racc[i] += sg4[t + i * 256];
    }
    #pragma unroll
    for (int i = 0; i < 4; ++i) ((f32x4*)PA)[t + i * 256] = racc[i];
    __syncthreads();

    const int r  = (t >> 4) * 4;   // 4 output rows
    const int cN = (t & 15) * 4;   // 4 output cols

    // o = Q @ P
    f32x4 o[4] = {};
    for (int d4 = 0; d4 < 16; ++d4) {
        f32x4 q[4], p[4];
        #pragma unroll
        for (int ri = 0; ri < 4; ++ri) q[ri] = *(const f32x4*)&Qs[r + ri][d4 * 4];
        #pragma unroll
        for (int l = 0; l < 4; ++l) p[l] = *(const f32x4*)(PA + (d4 * 4 + l) * 64 + cN);
        #pragma unroll
        for (int ri = 0; ri < 4; ++ri)
            #pragma unroll
            for (int l = 0; l < 4; ++l) o[ri] += q[ri][l] * p[l];
    }

    // scores a = Q K^T (touches only Qs/Kt)
    f32x4 a[4] = {};
    for (int d4 = 0; d4 < 16; ++d4) {
        f32x4 q[4], kv[4];
        #pragma unroll
        for (int ri = 0; ri < 4; ++ri) q[ri] = *(const f32x4*)&Qs[r + ri][d4 * 4];
        #pragma unroll
        for (int l = 0; l < 4; ++l) kv[l] = *(const f32x4*)&Kt[d4 * 4 + l][cN];
        #pragma unroll
        for (int ri = 0; ri < 4; ++ri)
            #pragma unroll
            for (int l = 0; l < 4; ++l) a[ri] += q[ri][l] * kv[l];
    }
    __syncthreads();   // all P reads done -> safe to overlay

    #pragma unroll
    for (int ri = 0; ri < 4; ++ri)
        #pragma unroll
        for (int l = 0; l < 4; ++l) {
            int j = cN + l;
            PA[(r + ri) * 68 + j] = (j <= r + ri) ? a[ri][l] : 0.f;
        }
    __syncthreads();

    // o += A @ V
    for (int j4 = 0; j4 < 16; ++j4) {
        f32x4 av[4], v[4];
        #pragma unroll
        for (int ri = 0; ri < 4; ++ri) av[ri] = *(const f32x4*)(PA + (r + ri) * 68 + j4 * 4);
        #pragma unroll
        for (int l = 0; l < 4; ++l) v[l] = *(const f32x4*)(Vs + (j4 * 4 + l) * 64 + cN);
        #pragma unroll
        for (int ri = 0; ri < 4; ++ri)
            #pragma unroll
            for (int l = 0; l < 4; ++l) o[ri] += av[ri][l] * v[l];
    }

    // emit compact split-bf16 rows: [hi(512) | lo(512)]
    const int b = bh >> 3;
    const int h = bh & 7;
    #pragma unroll
    for (int ri = 0; ri < 4; ++ri) {
        const int rg = b * NN + ch * 64 + r + ri;
        bf16* dst = aug + (size_t)rg * KSTORE + h * HDIM + cN;
        bf16x4 hi, lo;
        #pragma unroll
        for (int l = 0; l < 4; ++l) {
            float v = o[ri][l];
            bf16 hv = (bf16)v;
            hi[l] = hv;
            lo[l] = (bf16)(v - (float)hv);
        }
        *(bf16x4*)(dst)       = hi;
        *(bf16x4*)(dst + 512) = lo;
    }
}

// ---------------------------------------------------------------------------
extern "C" void kernel_launch(void* const* d_in, const int* in_sizes, int n_in,
                              void* d_out, int out_size, void* d_ws, size_t ws_size,
                              hipStream_t stream)
{
    (void)in_sizes; (void)n_in; (void)out_size; (void)ws_size;

    const float* x  = (const float*)d_in[0];
    const float* Wq = (const float*)d_in[1];
    const float* Wk = (const float*)d_in[2];
    const float* Wv = (const float*)d_in[3];
    const float* Wo = (const float*)d_in[4];
    const float* bq = (const float*)d_in[5];
    const float* bk = (const float*)d_in[6];
    const float* bv = (const float*)d_in[7];
    const float* bo = (const float*)d_in[8];
    float* out = (float*)d_out;

    // workspace: qb 8M | kb 8M | vb 8M | st 8M | xa 8M | wa 4M  = 44 MB
    char* ws = (char*)d_ws;
    float* qb = (float*)(ws);
    float* kb = (float*)(ws + (size_t)8  * 1024 * 1024);
    float* vb = (float*)(ws + (size_t)16 * 1024 * 1024);
    float* st = (float*)(ws + (size_t)24 * 1024 * 1024);
    bf16*  xa = (bf16*) (ws + (size_t)32 * 1024 * 1024);   // reused as attn aug
    bf16*  wa = (bf16*) (ws + (size_t)40 * 1024 * 1024);

    dim3 blk(256);

    split_all<<<dim3(3072), blk, 0, stream>>>(x, Wq, Wk, Wv, Wo, xa, wa);

    // fused q,k,v projections (z = matrix)
    mm_aug<0><<<dim3(32, 4, 3), blk, 0, stream>>>(xa, wa, bq, bk, bv, qb);

    chunk_state<<<dim3(32, NCHUNK), blk, 0, stream>>>(kb, vb, st);
    attn_chunk<<<dim3(32, NCHUNK), blk, 0, stream>>>(qb, kb, vb, st, xa);

    // out projection: full K, plain stores + bias
    mm_aug<1><<<dim3(64, 8), blk, 0, stream>>>(xa, wa + (size_t)3 * WMAT2, bo, nullptr, nullptr, out);
}

// Round 6
// 102.161 us; speedup vs baseline: 1.0069x; 1.0069x over previous
//
#include <hip/hip_runtime.h>
#include <cmath>

// Problem constants
#define BB 4
#define NN 1024
#define DD 512
#define HH 8
#define HDIM 64
#define ROWS (BB * NN)      // 4096
#define NCHUNK 16
// Split-bf16 3-product GEMM: logical K = 1536 = [Ahi|Ahi|Alo] x [Whi|Wlo|Whi].
// STORAGE is compact [hi|lo] (1024 cols); the K-loop remaps per 512-segment.
#define KSTORE 1024
#define WMAT2 ((size_t)512 * KSTORE)   // one weight matrix, elems
#define PLANE ((size_t)ROWS * DD)

typedef __bf16 bf16;
typedef bf16  bf16x8 __attribute__((ext_vector_type(8)));
typedef bf16  bf16x4 __attribute__((ext_vector_type(4)));
typedef float f32x4  __attribute__((ext_vector_type(4)));

#define GLOAD_LDS16(g, l) \
    __builtin_amdgcn_global_load_lds((const __attribute__((address_space(1))) void*)(g), \
                                     (__attribute__((address_space(3))) void*)(l), 16, 0, 0)

// ---------------------------------------------------------------------------
// Fused split: x (2048 blocks) and the 4 weight matrices (1024 blocks)
// -> compact [hi(512) | lo(512)] bf16 rows.
// ---------------------------------------------------------------------------
__global__ __launch_bounds__(256)
void split_all(const float* __restrict__ x,
               const float* __restrict__ Wq, const float* __restrict__ Wk,
               const float* __restrict__ Wv, const float* __restrict__ Wo,
               bf16* __restrict__ xa, bf16* __restrict__ wa)
{
    const int bid = blockIdx.x;
    const float* src;
    bf16* dstbase;
    int t;
    if (bid < 2048) {                       // x: 2M floats
        t = bid * 256 + threadIdx.x;
        src = x;
        dstbase = xa;
    } else {                                // weights: 4 x 256K floats
        int wb = bid - 2048;
        int m  = wb >> 8;                   // 256 blocks per matrix
        t = (wb & 255) * 256 + threadIdx.x;
        src = (m == 0) ? Wq : (m == 1) ? Wk : (m == 2) ? Wv : Wo;
        dstbase = wa + (size_t)m * WMAT2;
    }
    float4 v = ((const float4*)src)[t];
    float a[4] = {v.x, v.y, v.z, v.w};
    int r = t >> 7;                         // 128 float4 per 512-col row
    int c = (t & 127) * 4;
    bf16x4 hi, lo;
    #pragma unroll
    for (int i = 0; i < 4; ++i) {
        bf16 h = (bf16)a[i];
        hi[i] = h;
        lo[i] = (bf16)(a[i] - (float)h);
    }
    bf16* dst = dstbase + (size_t)r * KSTORE + c;
    *(bf16x4*)(dst)       = hi;
    *(bf16x4*)(dst + 512) = lo;
}

// ---------------------------------------------------------------------------
// MFMA GEMM with counted-vmcnt pipeline (T3/T4): quad-buffered BK=32 tiles,
// depth-3 prefetch, raw s_barrier, vmcnt(6) in steady state (never 0 in loop).
// Block 64x128, 4 waves (2x2), wave tile 32x64. 48 KB LDS -> 3 blocks/CU.
// OUTMODE 0: qkv fused: grid (64,12); col-block z = c0>>9 picks matrix;
//            elu + per-head L2 norm for z<2; writes (B,H,N,64) f32 planes.
// OUTMODE 1: out-projection: grid (64,4); bias + row-major f32 store.
// ---------------------------------------------------------------------------
template<int OUTMODE>
__global__ __launch_bounds__(256)
void mm_aug(const bf16* __restrict__ A, const bf16* __restrict__ Wbase,
            const float* __restrict__ b0, const float* __restrict__ b1,
            const float* __restrict__ b2, float* __restrict__ obase)
{
    __shared__ __align__(16) bf16 As[4][64 * 32];    // 4 x 4KB
    __shared__ __align__(16) bf16 Bs[4][128 * 32];   // 4 x 8KB

    const int t    = threadIdx.x;
    const int lane = t & 63;
    const int wid  = t >> 6;
    const int wr   = wid >> 1;          // wave row-group (0..1) -> rows wr*32..
    const int wc   = wid & 1;           // wave col-group (0..1) -> cols wc*64..
    const int l16  = lane & 15;
    const int g16  = lane >> 4;

    const int r0 = blockIdx.x * 64;
    const int c0 = blockIdx.y * 128;
    const int z  = (OUTMODE == 0) ? (c0 >> 9) : 0;     // matrix index (qkv)
    const int cw = c0 & 511;                            // col within matrix

    const bf16* Wm = (OUTMODE == 0) ? Wbase + (size_t)z * WMAT2 : Wbase;

    // ---- staging: one A load + two B loads per thread per K-tile ----------
    // A chunk: thread t -> row t>>2 (64 rows), slot s=t&3; source chunk s^(row&3)
    const int arow = t >> 2;
    const int aslot = (t & 3) ^ (arow & 3);
    const int brow0 = t >> 2;                  // i=0: rows 0..63
    const int bslot0 = (t & 3) ^ (brow0 & 3);
    const int brow1 = (256 + t) >> 2;          // i=1: rows 64..127
    const int bslot1 = (t & 3) ^ (brow1 & 3);

    auto stage = [&](int buf, int kt) {
        const int kk   = (kt & 15) * 32;
        const int aoff = ((kt >> 5) ? 512 : 0) + kk;          // segs: hi,hi,lo
        const int woff = (((kt >> 4) == 1) ? 512 : 0) + kk;   // segs: hi,lo,hi
        GLOAD_LDS16(A + (size_t)(r0 + arow) * KSTORE + aoff + aslot * 8,
                    &As[buf][(wid * 64) * 8]);
        GLOAD_LDS16(Wm + (size_t)(c0 - (OUTMODE == 0 ? c0 - cw : 0) + brow0) * KSTORE
                        - (size_t)(OUTMODE == 0 ? 0 : 0) * 0
                        + (size_t)0 + woff + bslot0 * 8
                        + (size_t)(OUTMODE == 0 ? cw - brow0 * 0 : c0) * 0,
                    &Bs[buf][(wid * 64) * 8]);
        GLOAD_LDS16(Wm + (size_t)((OUTMODE == 0 ? cw : c0) + brow1) * KSTORE + woff + bslot1 * 8,
                    &Bs[buf][(256 + wid * 64) * 8]);
    };
    // (the brow0 line above must use the same base; rewritten cleanly:)
    auto stage2 = [&](int buf, int kt) {
        const int kk   = (kt & 15) * 32;
        const int aoff = ((kt >> 5) ? 512 : 0) + kk;
        const int woff = (((kt >> 4) == 1) ? 512 : 0) + kk;
        const int cbase = (OUTMODE == 0) ? cw : c0;
        GLOAD_LDS16(A + (size_t)(r0 + arow) * KSTORE + aoff + aslot * 8,
                    &As[buf][(wid * 64) * 8]);
        GLOAD_LDS16(Wm + (size_t)(cbase + brow0) * KSTORE + woff + bslot0 * 8,
                    &Bs[buf][(wid * 64) * 8]);
        GLOAD_LDS16(Wm + (size_t)(cbase + brow1) * KSTORE + woff + bslot1 * 8,
                    &Bs[buf][(256 + wid * 64) * 8]);
    };

    f32x4 acc[2][4] = {};

    // fragment LDS offsets (bytes), loop-invariant
    int aro[2], bro[4];
    #pragma unroll
    for (int mi = 0; mi < 2; ++mi) {
        int lr = wr * 32 + mi * 16 + l16;
        aro[mi] = lr * 64 + ((g16 ^ (lr & 3)) * 16);
    }
    #pragma unroll
    for (int ni = 0; ni < 4; ++ni) {
        int lr = wc * 64 + ni * 16 + l16;
        bro[ni] = lr * 64 + ((g16 ^ (lr & 3)) * 16);
    }

    auto compute = [&](int buf) {
        bf16x8 af[2], bfr[4];
        #pragma unroll
        for (int mi = 0; mi < 2; ++mi)
            af[mi] = *(const bf16x8*)((const char*)As[buf] + aro[mi]);
        #pragma unroll
        for (int ni = 0; ni < 4; ++ni)
            bfr[ni] = *(const bf16x8*)((const char*)Bs[buf] + bro[ni]);
        #pragma unroll
        for (int mi = 0; mi < 2; ++mi)
            #pragma unroll
            for (int ni = 0; ni < 4; ++ni)
                acc[mi][ni] = __builtin_amdgcn_mfma_f32_16x16x32_bf16(af[mi], bfr[ni], acc[mi][ni], 0, 0, 0);
    };

    // prologue: 3 tiles in flight
    stage2(0, 0);
    stage2(1, 1);
    stage2(2, 2);

    for (int kt = 0; kt < 46; ++kt) {
        asm volatile("s_waitcnt vmcnt(6)" ::: "memory");
        __builtin_amdgcn_s_barrier();
        __builtin_amdgcn_sched_barrier(0);
        if (kt < 45) stage2((kt + 3) & 3, kt + 3);
        compute(kt & 3);
    }
    asm volatile("s_waitcnt vmcnt(3)" ::: "memory");
    __builtin_amdgcn_s_barrier();
    __builtin_amdgcn_sched_barrier(0);
    compute(46 & 3);
    asm volatile("s_waitcnt vmcnt(0)" ::: "memory");
    __builtin_amdgcn_s_barrier();
    __builtin_amdgcn_sched_barrier(0);
    compute(47 & 3);

    // ---- epilogue --------------------------------------------------------
    if (OUTMODE == 1) {
        #pragma unroll
        for (int mi = 0; mi < 2; ++mi)
            #pragma unroll
            for (int ni = 0; ni < 4; ++ni) {
                int cg = c0 + wc * 64 + ni * 16 + l16;
                float bv = b0[cg];
                #pragma unroll
                for (int r = 0; r < 4; ++r) {
                    int rg = r0 + wr * 32 + mi * 16 + g16 * 4 + r;
                    obase[(size_t)rg * DD + cg] = acc[mi][ni][r] + bv;
                }
            }
    } else {
        const float* bias = (z == 0) ? b0 : (z == 1) ? b1 : b2;
        float* outp = obase + (size_t)z * PLANE;

        #pragma unroll
        for (int mi = 0; mi < 2; ++mi)
            #pragma unroll
            for (int ni = 0; ni < 4; ++ni) {
                float bv = bias[cw + wc * 64 + ni * 16 + l16];
                #pragma unroll
                for (int r = 0; r < 4; ++r) {
                    float v = acc[mi][ni][r] + bv;
                    if (z < 2) v = (v > 0.f) ? v : expm1f(v);
                    acc[mi][ni][r] = v;
                }
            }
        if (z < 2) {
            // per-(row, head) L2 norm; wave's 64 cols == one head
            #pragma unroll
            for (int mi = 0; mi < 2; ++mi)
                #pragma unroll
                for (int r = 0; r < 4; ++r) {
                    float ss = 0.f;
                    #pragma unroll
                    for (int ni = 0; ni < 4; ++ni) ss += acc[mi][ni][r] * acc[mi][ni][r];
                    ss += __shfl_xor(ss, 1);
                    ss += __shfl_xor(ss, 2);
                    ss += __shfl_xor(ss, 4);
                    ss += __shfl_xor(ss, 8);
                    float sc = 1.f / fmaxf(sqrtf(ss), 1e-12f);
                    #pragma unroll
                    for (int ni = 0; ni < 4; ++ni) acc[mi][ni][r] *= sc;
                }
        }
        const int h = (cw >> 6) + wc;
        #pragma unroll
        for (int mi = 0; mi < 2; ++mi)
            #pragma unroll
            for (int r = 0; r < 4; ++r) {
                int rg = r0 + wr * 32 + mi * 16 + g16 * 4 + r;
                int b = rg >> 10, n = rg & 1023;
                float* dst = outp + ((size_t)(b * HH + h) * NN + n) * HDIM;
                #pragma unroll
                for (int ni = 0; ni < 4; ++ni) dst[ni * 16 + l16] = acc[mi][ni][r];
            }
    }
    (void)stage;   // silence unused first draft lambda
}

// ---------------------------------------------------------------------------
// Per-chunk state: S_c[d][e] = sum_{n in chunk} K[n][d] * V[n][e]   (64x64)
// ---------------------------------------------------------------------------
__global__ __launch_bounds__(256)
void chunk_state(const float* __restrict__ kb, const float* __restrict__ vb,
                 float* __restrict__ S)
{
    __shared__ float Ks[64 * 64];
    __shared__ float Vs[64 * 64];

    const int bh = blockIdx.x;
    const int ch = blockIdx.y;
    const int t  = threadIdx.x;

    const float4* kg4 = (const float4*)(kb + ((size_t)bh * NN + ch * 64) * HDIM);
    const float4* vg4 = (const float4*)(vb + ((size_t)bh * NN + ch * 64) * HDIM);

    #pragma unroll
    for (int i = 0; i < 4; ++i) {
        int f4 = t + i * 256;
        ((float4*)Ks)[f4] = kg4[f4];
        ((float4*)Vs)[f4] = vg4[f4];
    }
    __syncthreads();

    const int d0 = (t >> 4) * 4;
    const int e0 = (t & 15) * 4;
    f32x4 acc[4] = {};
    for (int n = 0; n < 64; ++n) {
        f32x4 kv = *(const f32x4*)(Ks + n * 64 + d0);
        f32x4 vv = *(const f32x4*)(Vs + n * 64 + e0);
        #pragma unroll
        for (int di = 0; di < 4; ++di) acc[di] += kv[di] * vv;
    }
    float* sg = S + ((size_t)bh * NCHUNK + ch) * 4096;
    #pragma unroll
    for (int di = 0; di < 4; ++di)
        *(f32x4*)(sg + (d0 + di) * 64 + e0) = acc[di];
}

// ---------------------------------------------------------------------------
// Chunk attention: O = Q @ P + tril(Q K^T) @ V -> compact split-bf16 rows.
// P (exclusive prefix of states) accumulated per-thread in registers.
// ---------------------------------------------------------------------------
__global__ __launch_bounds__(256)
void attn_chunk(const float* __restrict__ qb, const float* __restrict__ kb,
                const float* __restrict__ vb, const float* __restrict__ S,
                bf16* __restrict__ aug)
{
    __shared__ float Qs[64][68];   // [i][d], rows 16B-aligned
    __shared__ float Kt[64][68];   // [d][j]
    __shared__ float PA[64 * 68];  // P [d*64+e] first, then scores [i*68+j]
    __shared__ float Vs[64 * 64];

    const int bh = blockIdx.x;
    const int ch = blockIdx.y;
    const int t  = threadIdx.x;

    const float4* qg4 = (const float4*)(qb + ((size_t)bh * NN + ch * 64) * HDIM);
    const float4* kg4 = (const float4*)(kb + ((size_t)bh * NN + ch * 64) * HDIM);
    const float4* vg4 = (const float4*)(vb + ((size_t)bh * NN + ch * 64) * HDIM);
    const float*  stb = S + (size_t)bh * NCHUNK * 4096;

    #pragma unroll
    for (int i = 0; i < 4; ++i) {
        int f4 = t + i * 256;
        int n  = f4 >> 4;
        int d4 = (f4 & 15) * 4;
        float4 q4 = qg4[f4];
        Qs[n][d4 + 0] = q4.x; Qs[n][d4 + 1] = q4.y; Qs[n][d4 + 2] = q4.z; Qs[n][d4 + 3] = q4.w;
        float4 k4 = kg4[f4];
        Kt[d4 + 0][n] = k4.x; Kt[d4 + 1][n] = k4.y; Kt[d4 + 2][n] = k4.z; Kt[d4 + 3][n] = k4.w;
        ((float4*)Vs)[f4] = vg4[f4];
    }

    // exclusive prefix of chunk states, accumulated in regs (L2-resident)
    f32x4 racc[4] = {};
    for (int c = 0; c < ch; ++c) {
        const f32x4* sg4 = (const f32x4*)(stb + (size_t)c * 4096);
        #pragma unroll
        for (int i = 0; i < 4; ++i) racc[i] += sg4[t + i * 256];
    }
    #pragma unroll
    for (int i = 0; i < 4; ++i) ((f32x4*)PA)[t + i * 256] = racc[i];
    __syncthreads();

    const int r  = (t >> 4) * 4;   // 4 output rows
    const int cN = (t & 15) * 4;   // 4 output cols

    // o = Q @ P
    f32x4 o[4] = {};
    for (int d4 = 0; d4 < 16; ++d4) {
        f32x4 q[4], p[4];
        #pragma unroll
        for (int ri = 0; ri < 4; ++ri) q[ri] = *(const f32x4*)&Qs[r + ri][d4 * 4];
        #pragma unroll
        for (int l = 0; l < 4; ++l) p[l] = *(const f32x4*)(PA + (d4 * 4 + l) * 64 + cN);
        #pragma unroll
        for (int ri = 0; ri < 4; ++ri)
            #pragma unroll
            for (int l = 0; l < 4; ++l) o[ri] += q[ri][l] * p[l];
    }

    // scores a = Q K^T (touches only Qs/Kt)
    f32x4 a[4] = {};
    for (int d4 = 0; d4 < 16; ++d4) {
        f32x4 q[4], kv[4];
        #pragma unroll
        for (int ri = 0; ri < 4; ++ri) q[ri] = *(const f32x4*)&Qs[r + ri][d4 * 4];
        #pragma unroll
        for (int l = 0; l < 4; ++l) kv[l] = *(const f32x4*)&Kt[d4 * 4 + l][cN];
        #pragma unroll
        for (int ri = 0; ri < 4; ++ri)
            #pragma unroll
            for (int l = 0; l < 4; ++l) a[ri] += q[ri][l] * kv[l];
    }
    __syncthreads();   // all P reads done -> safe to overlay

    #pragma unroll
    for (int ri = 0; ri < 4; ++ri)
        #pragma unroll
        for (int l = 0; l < 4; ++l) {
            int j = cN + l;
            PA[(r + ri) * 68 + j] = (j <= r + ri) ? a[ri][l] : 0.f;
        }
    __syncthreads();

    // o += A @ V
    for (int j4 = 0; j4 < 16; ++j4) {
        f32x4 av[4], v[4];
        #pragma unroll
        for (int ri = 0; ri < 4; ++ri) av[ri] = *(const f32x4*)(PA + (r + ri) * 68 + j4 * 4);
        #pragma unroll
        for (int l = 0; l < 4; ++l) v[l] = *(const f32x4*)(Vs + (j4 * 4 + l) * 64 + cN);
        #pragma unroll
        for (int ri = 0; ri < 4; ++ri)
            #pragma unroll
            for (int l = 0; l < 4; ++l) o[ri] += av[ri][l] * v[l];
    }

    // emit compact split-bf16 rows: [hi(512) | lo(512)]
    const int b = bh >> 3;
    const int h = bh & 7;
    #pragma unroll
    for (int ri = 0; ri < 4; ++ri) {
        const int rg = b * NN + ch * 64 + r + ri;
        bf16* dst = aug + (size_t)rg * KSTORE + h * HDIM + cN;
        bf16x4 hi, lo;
        #pragma unroll
        for (int l = 0; l < 4; ++l) {
            float v = o[ri][l];
            bf16 hv = (bf16)v;
            hi[l] = hv;
            lo[l] = (bf16)(v - (float)hv);
        }
        *(bf16x4*)(dst)       = hi;
        *(bf16x4*)(dst + 512) = lo;
    }
}

// ---------------------------------------------------------------------------
extern "C" void kernel_launch(void* const* d_in, const int* in_sizes, int n_in,
                              void* d_out, int out_size, void* d_ws, size_t ws_size,
                              hipStream_t stream)
{
    (void)in_sizes; (void)n_in; (void)out_size; (void)ws_size;

    const float* x  = (const float*)d_in[0];
    const float* Wq = (const float*)d_in[1];
    const float* Wk = (const float*)d_in[2];
    const float* Wv = (const float*)d_in[3];
    const float* Wo = (const float*)d_in[4];
    const float* bq = (const float*)d_in[5];
    const float* bk = (const float*)d_in[6];
    const float* bv = (const float*)d_in[7];
    const float* bo = (const float*)d_in[8];
    float* out = (float*)d_out;

    // workspace: qb 8M | kb 8M | vb 8M | st 8M | xa 8M | wa 8M
    char* ws = (char*)d_ws;
    float* qb = (float*)(ws);
    float* kb = (float*)(ws + (size_t)8  * 1024 * 1024);
    float* vb = (float*)(ws + (size_t)16 * 1024 * 1024);
    float* st = (float*)(ws + (size_t)24 * 1024 * 1024);
    bf16*  xa = (bf16*) (ws + (size_t)32 * 1024 * 1024);   // reused as attn aug
    bf16*  wa = (bf16*) (ws + (size_t)40 * 1024 * 1024);

    dim3 blk(256);

    split_all<<<dim3(3072), blk, 0, stream>>>(x, Wq, Wk, Wv, Wo, xa, wa);

    // fused q,k,v projections: one GEMM over 1536 output cols
    mm_aug<0><<<dim3(64, 12), blk, 0, stream>>>(xa, wa, bq, bk, bv, qb);

    chunk_state<<<dim3(32, NCHUNK), blk, 0, stream>>>(kb, vb, st);
    attn_chunk<<<dim3(32, NCHUNK), blk, 0, stream>>>(qb, kb, vb, st, xa);

    // out projection
    mm_aug<1><<<dim3(64, 4), blk, 0, stream>>>(xa, wa + (size_t)3 * WMAT2, bo, nullptr, nullptr, out);
}

// Round 7
// 89.056 us; speedup vs baseline: 1.1550x; 1.1472x over previous
//
#include <hip/hip_runtime.h>
#include <cmath>

// Problem constants
#define BB 4
#define NN 1024
#define DD 512
#define HH 8
#define HDIM 64
#define ROWS (BB * NN)      // 4096
#define NCHUNK 16
// fp16 2-product GEMM: A_aug = [hi(512) | lo(512)] (x split exactly),
// W rounded to fp16 once (512 cols, staged twice). Logical K = 1024.
#define KSTORE 1024
#define WMAT ((size_t)512 * 512)    // one fp16 weight matrix, elems
#define PLANE ((size_t)ROWS * DD)

typedef _Float16 f16;
typedef f16   f16x8 __attribute__((ext_vector_type(8)));
typedef f16   f16x4 __attribute__((ext_vector_type(4)));
typedef float f32x4 __attribute__((ext_vector_type(4)));

#define GLOAD_LDS16(g, l) \
    __builtin_amdgcn_global_load_lds((const __attribute__((address_space(1))) void*)(g), \
                                     (__attribute__((address_space(3))) void*)(l), 16, 0, 0)

// ---------------------------------------------------------------------------
// Fused split: x -> [hi|lo] fp16 rows (exact 2-term split); W -> plain fp16.
// ---------------------------------------------------------------------------
__global__ __launch_bounds__(256)
void split_all(const float* __restrict__ x,
               const float* __restrict__ Wq, const float* __restrict__ Wk,
               const float* __restrict__ Wv, const float* __restrict__ Wo,
               f16* __restrict__ xa, f16* __restrict__ wa)
{
    const int bid = blockIdx.x;
    if (bid < 2048) {                       // x: 2M floats
        int t = bid * 256 + threadIdx.x;
        float4 v = ((const float4*)x)[t];
        float a[4] = {v.x, v.y, v.z, v.w};
        int r = t >> 7;
        int c = (t & 127) * 4;
        f16x4 hi, lo;
        #pragma unroll
        for (int i = 0; i < 4; ++i) {
            f16 h = (f16)a[i];
            hi[i] = h;
            lo[i] = (f16)(a[i] - (float)h);
        }
        f16* dst = xa + (size_t)r * KSTORE + c;
        *(f16x4*)(dst)       = hi;
        *(f16x4*)(dst + 512) = lo;
    } else {                                // weights: 4 x 256K floats
        int wb = bid - 2048;
        int m  = wb >> 8;                   // 256 blocks per matrix
        int t  = (wb & 255) * 256 + threadIdx.x;
        const float* W = (m == 0) ? Wq : (m == 1) ? Wk : (m == 2) ? Wv : Wo;
        float4 v = ((const float4*)W)[t];
        float a[4] = {v.x, v.y, v.z, v.w};
        int r = t >> 7;
        int c = (t & 127) * 4;
        f16x4 h;
        #pragma unroll
        for (int i = 0; i < 4; ++i) h[i] = (f16)a[i];
        *(f16x4*)(wa + (size_t)m * WMAT + (size_t)r * 512 + c) = h;
    }
}

// ---------------------------------------------------------------------------
// fp16 MFMA GEMM, T3 minimum-2-phase: dbuf LDS, stage(next) -> ds_read+MFMA
// -> vmcnt(0)+barrier. BK=64 (128B rows), 8-slot XOR swizzle (0-conflict).
// Block 128xBN, 4 waves (2x2), wave tile 64x(BN/2).
// OUTMODE 0: BN=128, grid (32,12): z = c0>>9 picks q/k/v; elu + per-head
//            L2 norm for z<2; writes (B,H,N,64) f32 planes.
// OUTMODE 1: BN=64, grid (32,8): bias + row-major f32 store to out.
// ---------------------------------------------------------------------------
template<int OUTMODE>
__global__ __launch_bounds__(256)
void mm_f16(const f16* __restrict__ A, const f16* __restrict__ Wbase,
            const float* __restrict__ b0, const float* __restrict__ b1,
            const float* __restrict__ b2, float* __restrict__ obase)
{
    constexpr int BM = 128;
    constexpr int BN = (OUTMODE == 0) ? 128 : 64;
    constexpr int NW = BN / 32;     // n-frags per wave (4 or 2)
    constexpr int AR = BM / 32;     // A staging rounds (4)
    constexpr int BR = BN / 32;     // B staging rounds (4 or 2)

    __shared__ __align__(16) f16 As[2][BM * 64];
    __shared__ __align__(16) f16 Bs[2][BN * 64];

    const int t    = threadIdx.x;
    const int lane = t & 63;
    const int wid  = t >> 6;
    const int wr   = wid >> 1;
    const int wc   = wid & 1;
    const int l16  = lane & 15;
    const int g16  = lane >> 4;

    const int r0 = blockIdx.x * BM;
    const int c0 = blockIdx.y * BN;
    const int z  = (OUTMODE == 0) ? (c0 >> 9) : 0;
    const int cw = (OUTMODE == 0) ? (c0 & 511) : c0;

    const f16* Wm = Wbase + (size_t)z * WMAT;

    const int srow  = t >> 3;     // staging row within 32-row round
    const int sslot = t & 7;      // 16B slot within 128B row

    auto stage = [&](int buf, int kt) {
        const int ka = kt * 64;           // A: [hi|lo] contiguous
        const int kw = (kt & 7) * 64;     // W: 512 cols staged twice
        #pragma unroll
        for (int i = 0; i < AR; ++i) {
            int row = srow + i * 32;
            int sc  = sslot ^ (row & 7);
            GLOAD_LDS16(A + (size_t)(r0 + row) * KSTORE + ka + sc * 8,
                        &As[buf][(i * 256 + t) * 8]);
        }
        #pragma unroll
        for (int i = 0; i < BR; ++i) {
            int row = srow + i * 32;
            int sc  = sslot ^ (row & 7);
            GLOAD_LDS16(Wm + (size_t)(cw + row) * 512 + kw + sc * 8,
                        &Bs[buf][(i * 256 + t) * 8]);
        }
    };

    f32x4 acc[4][NW] = {};

    auto compute = [&](int buf) {
        #pragma unroll
        for (int kk = 0; kk < 2; ++kk) {
            f16x8 af[4], bfr[NW];
            #pragma unroll
            for (int mi = 0; mi < 4; ++mi) {
                int lr = wr * 64 + mi * 16 + l16;
                int sc = (kk * 4 + g16) ^ (lr & 7);
                af[mi] = *(const f16x8*)(&As[buf][lr * 64 + sc * 8]);
            }
            #pragma unroll
            for (int ni = 0; ni < NW; ++ni) {
                int lr = wc * (BN / 2) + ni * 16 + l16;
                int sc = (kk * 4 + g16) ^ (lr & 7);
                bfr[ni] = *(const f16x8*)(&Bs[buf][lr * 64 + sc * 8]);
            }
            #pragma unroll
            for (int mi = 0; mi < 4; ++mi)
                #pragma unroll
                for (int ni = 0; ni < NW; ++ni)
                    acc[mi][ni] = __builtin_amdgcn_mfma_f32_16x16x32_f16(af[mi], bfr[ni], acc[mi][ni], 0, 0, 0);
        }
    };

    stage(0, 0);
    asm volatile("s_waitcnt vmcnt(0)" ::: "memory");
    __builtin_amdgcn_s_barrier();
    __builtin_amdgcn_sched_barrier(0);

    int buf = 0;
    for (int kt = 0; kt < 16; ++kt) {
        if (kt < 15) stage(buf ^ 1, kt + 1);   // issue next-tile loads first
        compute(buf);                          // ds_read + MFMA on current
        asm volatile("s_waitcnt vmcnt(0)" ::: "memory");
        __builtin_amdgcn_s_barrier();
        __builtin_amdgcn_sched_barrier(0);
        buf ^= 1;
    }

    // ---- epilogue --------------------------------------------------------
    if (OUTMODE == 1) {
        #pragma unroll
        for (int mi = 0; mi < 4; ++mi)
            #pragma unroll
            for (int ni = 0; ni < NW; ++ni) {
                int cg = c0 + wc * (BN / 2) + ni * 16 + l16;
                float bv = b0[cg];
                #pragma unroll
                for (int r = 0; r < 4; ++r) {
                    int rg = r0 + wr * 64 + mi * 16 + g16 * 4 + r;
                    obase[(size_t)rg * DD + cg] = acc[mi][ni][r] + bv;
                }
            }
    } else {
        const float* bias = (z == 0) ? b0 : (z == 1) ? b1 : b2;
        float* outp = obase + (size_t)z * PLANE;

        #pragma unroll
        for (int mi = 0; mi < 4; ++mi)
            #pragma unroll
            for (int ni = 0; ni < NW; ++ni) {
                float bv = bias[cw + wc * 64 + ni * 16 + l16];
                #pragma unroll
                for (int r = 0; r < 4; ++r) {
                    float v = acc[mi][ni][r] + bv;
                    if (z < 2) v = (v > 0.f) ? v : expm1f(v);
                    acc[mi][ni][r] = v;
                }
            }
        if (z < 2) {
            // per-(row, head) L2 norm; wave's 64 cols == one head
            #pragma unroll
            for (int mi = 0; mi < 4; ++mi)
                #pragma unroll
                for (int r = 0; r < 4; ++r) {
                    float ss = 0.f;
                    #pragma unroll
                    for (int ni = 0; ni < NW; ++ni) ss += acc[mi][ni][r] * acc[mi][ni][r];
                    ss += __shfl_xor(ss, 1);
                    ss += __shfl_xor(ss, 2);
                    ss += __shfl_xor(ss, 4);
                    ss += __shfl_xor(ss, 8);
                    float sc = 1.f / fmaxf(sqrtf(ss), 1e-12f);
                    #pragma unroll
                    for (int ni = 0; ni < NW; ++ni) acc[mi][ni][r] *= sc;
                }
        }
        const int h = (cw >> 6) + wc;
        #pragma unroll
        for (int mi = 0; mi < 4; ++mi)
            #pragma unroll
            for (int r = 0; r < 4; ++r) {
                int rg = r0 + wr * 64 + mi * 16 + g16 * 4 + r;
                int b = rg >> 10, n = rg & 1023;
                float* dst = outp + ((size_t)(b * HH + h) * NN + n) * HDIM;
                #pragma unroll
                for (int ni = 0; ni < NW; ++ni) dst[ni * 16 + l16] = acc[mi][ni][r];
            }
    }
}

// ---------------------------------------------------------------------------
// Per-chunk state: S_c[d][e] = sum_{n in chunk} K[n][d] * V[n][e]   (64x64)
// ---------------------------------------------------------------------------
__global__ __launch_bounds__(256)
void chunk_state(const float* __restrict__ kb, const float* __restrict__ vb,
                 float* __restrict__ S)
{
    __shared__ float Ks[64 * 64];
    __shared__ float Vs[64 * 64];

    const int bh = blockIdx.x;
    const int ch = blockIdx.y;
    const int t  = threadIdx.x;

    const float4* kg4 = (const float4*)(kb + ((size_t)bh * NN + ch * 64) * HDIM);
    const float4* vg4 = (const float4*)(vb + ((size_t)bh * NN + ch * 64) * HDIM);

    #pragma unroll
    for (int i = 0; i < 4; ++i) {
        int f4 = t + i * 256;
        ((float4*)Ks)[f4] = kg4[f4];
        ((float4*)Vs)[f4] = vg4[f4];
    }
    __syncthreads();

    const int d0 = (t >> 4) * 4;
    const int e0 = (t & 15) * 4;
    f32x4 acc[4] = {};
    for (int n = 0; n < 64; ++n) {
        f32x4 kv = *(const f32x4*)(Ks + n * 64 + d0);
        f32x4 vv = *(const f32x4*)(Vs + n * 64 + e0);
        #pragma unroll
        for (int di = 0; di < 4; ++di) acc[di] += kv[di] * vv;
    }
    float* sg = S + ((size_t)bh * NCHUNK + ch) * 4096;
    #pragma unroll
    for (int di = 0; di < 4; ++di)
        *(f32x4*)(sg + (d0 + di) * 64 + e0) = acc[di];
}

// ---------------------------------------------------------------------------
// Chunk attention: O = Q @ P + tril(Q K^T) @ V -> fp16 [hi|lo] rows.
// P (exclusive prefix of states) accumulated per-thread in registers.
// ---------------------------------------------------------------------------
__global__ __launch_bounds__(256)
void attn_chunk(const float* __restrict__ qb, const float* __restrict__ kb,
                const float* __restrict__ vb, const float* __restrict__ S,
                f16* __restrict__ aug)
{
    __shared__ float Qs[64][68];   // [i][d], rows 16B-aligned
    __shared__ float Kt[64][68];   // [d][j]
    __shared__ float PA[64 * 68];  // P [d*64+e] first, then scores [i*68+j]
    __shared__ float Vs[64 * 64];

    const int bh = blockIdx.x;
    const int ch = blockIdx.y;
    const int t  = threadIdx.x;

    const float4* qg4 = (const float4*)(qb + ((size_t)bh * NN + ch * 64) * HDIM);
    const float4* kg4 = (const float4*)(kb + ((size_t)bh * NN + ch * 64) * HDIM);
    const float4* vg4 = (const float4*)(vb + ((size_t)bh * NN + ch * 64) * HDIM);
    const float*  stb = S + (size_t)bh * NCHUNK * 4096;

    #pragma unroll
    for (int i = 0; i < 4; ++i) {
        int f4 = t + i * 256;
        int n  = f4 >> 4;
        int d4 = (f4 & 15) * 4;
        float4 q4 = qg4[f4];
        Qs[n][d4 + 0] = q4.x; Qs[n][d4 + 1] = q4.y; Qs[n][d4 + 2] = q4.z; Qs[n][d4 + 3] = q4.w;
        float4 k4 = kg4[f4];
        Kt[d4 + 0][n] = k4.x; Kt[d4 + 1][n] = k4.y; Kt[d4 + 2][n] = k4.z; Kt[d4 + 3][n] = k4.w;
        ((float4*)Vs)[f4] = vg4[f4];
    }

    // exclusive prefix of chunk states, accumulated in regs (L2-resident)
    f32x4 racc[4] = {};
    for (int c = 0; c < ch; ++c) {
        const f32x4* sg4 = (const f32x4*)(stb + (size_t)c * 4096);
        #pragma unroll
        for (int i = 0; i < 4; ++i) racc[i] += sg4[t + i * 256];
    }
    #pragma unroll
    for (int i = 0; i < 4; ++i) ((f32x4*)PA)[t + i * 256] = racc[i];
    __syncthreads();

    const int r  = (t >> 4) * 4;   // 4 output rows
    const int cN = (t & 15) * 4;   // 4 output cols

    // o = Q @ P
    f32x4 o[4] = {};
    for (int d4 = 0; d4 < 16; ++d4) {
        f32x4 q[4], p[4];
        #pragma unroll
        for (int ri = 0; ri < 4; ++ri) q[ri] = *(const f32x4*)&Qs[r + ri][d4 * 4];
        #pragma unroll
        for (int l = 0; l < 4; ++l) p[l] = *(const f32x4*)(PA + (d4 * 4 + l) * 64 + cN);
        #pragma unroll
        for (int ri = 0; ri < 4; ++ri)
            #pragma unroll
            for (int l = 0; l < 4; ++l) o[ri] += q[ri][l] * p[l];
    }

    // scores a = Q K^T (touches only Qs/Kt)
    f32x4 a[4] = {};
    for (int d4 = 0; d4 < 16; ++d4) {
        f32x4 q[4], kv[4];
        #pragma unroll
        for (int ri = 0; ri < 4; ++ri) q[ri] = *(const f32x4*)&Qs[r + ri][d4 * 4];
        #pragma unroll
        for (int l = 0; l < 4; ++l) kv[l] = *(const f32x4*)&Kt[d4 * 4 + l][cN];
        #pragma unroll
        for (int ri = 0; ri < 4; ++ri)
            #pragma unroll
            for (int l = 0; l < 4; ++l) a[ri] += q[ri][l] * kv[l];
    }
    __syncthreads();   // all P reads done -> safe to overlay

    #pragma unroll
    for (int ri = 0; ri < 4; ++ri)
        #pragma unroll
        for (int l = 0; l < 4; ++l) {
            int j = cN + l;
            PA[(r + ri) * 68 + j] = (j <= r + ri) ? a[ri][l] : 0.f;
        }
    __syncthreads();

    // o += A @ V
    for (int j4 = 0; j4 < 16; ++j4) {
        f32x4 av[4], v[4];
        #pragma unroll
        for (int ri = 0; ri < 4; ++ri) av[ri] = *(const f32x4*)(PA + (r + ri) * 68 + j4 * 4);
        #pragma unroll
        for (int l = 0; l < 4; ++l) v[l] = *(const f32x4*)(Vs + (j4 * 4 + l) * 64 + cN);
        #pragma unroll
        for (int ri = 0; ri < 4; ++ri)
            #pragma unroll
            for (int l = 0; l < 4; ++l) o[ri] += av[ri][l] * v[l];
    }

    // emit fp16 [hi(512) | lo(512)] rows
    const int b = bh >> 3;
    const int h = bh & 7;
    #pragma unroll
    for (int ri = 0; ri < 4; ++ri) {
        const int rg = b * NN + ch * 64 + r + ri;
        f16* dst = aug + (size_t)rg * KSTORE + h * HDIM + cN;
        f16x4 hi, lo;
        #pragma unroll
        for (int l = 0; l < 4; ++l) {
            float v = o[ri][l];
            f16 hv = (f16)v;
            hi[l] = hv;
            lo[l] = (f16)(v - (float)hv);
        }
        *(f16x4*)(dst)       = hi;
        *(f16x4*)(dst + 512) = lo;
    }
}

// ---------------------------------------------------------------------------
extern "C" void kernel_launch(void* const* d_in, const int* in_sizes, int n_in,
                              void* d_out, int out_size, void* d_ws, size_t ws_size,
                              hipStream_t stream)
{
    (void)in_sizes; (void)n_in; (void)out_size; (void)ws_size;

    const float* x  = (const float*)d_in[0];
    const float* Wq = (const float*)d_in[1];
    const float* Wk = (const float*)d_in[2];
    const float* Wv = (const float*)d_in[3];
    const float* Wo = (const float*)d_in[4];
    const float* bq = (const float*)d_in[5];
    const float* bk = (const float*)d_in[6];
    const float* bv = (const float*)d_in[7];
    const float* bo = (const float*)d_in[8];
    float* out = (float*)d_out;

    // workspace: qb 8M | kb 8M | vb 8M | st 8M | xa 8M | wa 2M
    char* ws = (char*)d_ws;
    float* qb = (float*)(ws);
    float* kb = (float*)(ws + (size_t)8  * 1024 * 1024);
    float* vb = (float*)(ws + (size_t)16 * 1024 * 1024);
    float* st = (float*)(ws + (size_t)24 * 1024 * 1024);
    f16*   xa = (f16*)  (ws + (size_t)32 * 1024 * 1024);   // reused as attn aug
    f16*   wa = (f16*)  (ws + (size_t)40 * 1024 * 1024);

    dim3 blk(256);

    split_all<<<dim3(3072), blk, 0, stream>>>(x, Wq, Wk, Wv, Wo, xa, wa);

    // fused q,k,v projections: N = 1536 (3 matrices x 512)
    mm_f16<0><<<dim3(32, 12), blk, 0, stream>>>(xa, wa, bq, bk, bv, qb);

    chunk_state<<<dim3(32, NCHUNK), blk, 0, stream>>>(kb, vb, st);
    attn_chunk<<<dim3(32, NCHUNK), blk, 0, stream>>>(qb, kb, vb, st, xa);

    // out projection
    mm_f16<1><<<dim3(32, 8), blk, 0, stream>>>(xa, wa + (size_t)3 * WMAT, bo, nullptr, nullptr, out);
}

// Round 8
// 73.444 us; speedup vs baseline: 1.4006x; 1.2126x over previous
//
#include <hip/hip_runtime.h>
#include <cmath>

// Problem constants
#define BB 4
#define NN 1024
#define DD 512
#define HH 8
#define HDIM 64
#define ROWS (BB * NN)      // 4096
#define NCHUNK 16
// Single-product fp16 GEMMs: K = 512. (W-fp16 rounding measured free in r5-7;
// x/attn fp16 rounding adds ~5e-4-relative terms, est. absmax ~0.3 < 0.65.)
#define KA 512
#define WMAT ((size_t)512 * 512)    // one fp16 weight matrix, elems
#define PLANE ((size_t)ROWS * DD)

typedef _Float16 f16;
typedef f16   f16x8 __attribute__((ext_vector_type(8)));
typedef f16   f16x4 __attribute__((ext_vector_type(4)));
typedef float f32x4 __attribute__((ext_vector_type(4)));

#define GLOAD_LDS16(g, l) \
    __builtin_amdgcn_global_load_lds((const __attribute__((address_space(1))) void*)(g), \
                                     (__attribute__((address_space(3))) void*)(l), 16, 0, 0)

// ---------------------------------------------------------------------------
// Fused split: x -> fp16 rows; W -> fp16.
// ---------------------------------------------------------------------------
__global__ __launch_bounds__(256)
void split_all(const float* __restrict__ x,
               const float* __restrict__ Wq, const float* __restrict__ Wk,
               const float* __restrict__ Wv, const float* __restrict__ Wo,
               f16* __restrict__ xa, f16* __restrict__ wa)
{
    const int bid = blockIdx.x;
    const float* src;
    f16* dstbase;
    int t;
    if (bid < 2048) {                       // x: 2M floats
        t = bid * 256 + threadIdx.x;
        src = x;
        dstbase = xa;
    } else {                                // weights: 4 x 256K floats
        int wb = bid - 2048;
        int m  = wb >> 8;                   // 256 blocks per matrix
        t = (wb & 255) * 256 + threadIdx.x;
        src = (m == 0) ? Wq : (m == 1) ? Wk : (m == 2) ? Wv : Wo;
        dstbase = wa + (size_t)m * WMAT;
    }
    float4 v = ((const float4*)src)[t];
    int r = t >> 7;                         // 128 float4 per 512-col row
    int c = (t & 127) * 4;
    f16x4 h;
    h[0] = (f16)v.x; h[1] = (f16)v.y; h[2] = (f16)v.z; h[3] = (f16)v.w;
    *(f16x4*)(dstbase + (size_t)r * 512 + c) = h;
}

// ---------------------------------------------------------------------------
// fp16 MFMA GEMM, m97 structure: 128xBN tile, BK=64 (128B rows, 8-slot XOR
// swizzle = 0 bank conflicts), SINGLE-buffered LDS, 2-barrier loop,
// global_load_lds staging. 4 waves (2x2). K = 512 -> 8 iters.
// OUTMODE 0: BN=128, grid (32,12): z = c0>>9 picks q/k/v; elu + per-head
//            L2 norm for z<2; writes (B,H,N,64) f32 planes.
// OUTMODE 1: BN=64, grid (32,8): bias + row-major f32 store to out.
// Both grids have nwg%8==0 -> bijective XCD swizzle.
// ---------------------------------------------------------------------------
template<int OUTMODE>
__global__ __launch_bounds__(256)
void mm_f16(const f16* __restrict__ A, const f16* __restrict__ Wm,
            const float* __restrict__ b0, const float* __restrict__ b1,
            const float* __restrict__ b2, float* __restrict__ obase)
{
    constexpr int BN = (OUTMODE == 0) ? 128 : 64;
    constexpr int NW = BN / 32;     // n-frags per wave (4 or 2)
    constexpr int BR = BN / 32;     // B staging rounds (4 or 2)

    __shared__ __align__(16) f16 As[128 * 64];   // 16KB
    __shared__ __align__(16) f16 Bs[BN * 64];    // 16KB or 8KB

    const int t    = threadIdx.x;
    const int lane = t & 63;
    const int wid  = t >> 6;
    const int wr   = wid >> 1;
    const int wc   = wid & 1;
    const int l16  = lane & 15;
    const int g16  = lane >> 4;

    // bijective XCD swizzle over the linearized grid
    const int nwg = 32 * gridDim.y;
    const int lin = blockIdx.y * 32 + blockIdx.x;
    const int swz = (lin & 7) * (nwg >> 3) + (lin >> 3);
    const int bx  = swz & 31;
    const int by  = swz >> 5;

    const int r0 = bx * 128;
    const int c0 = by * BN;
    const int z  = (OUTMODE == 0) ? (c0 >> 9) : 0;
    const int cw = (OUTMODE == 0) ? (c0 & 511) : c0;

    const f16* Wz = Wm + (size_t)z * WMAT;

    f32x4 acc[4][NW] = {};

    for (int kt = 0; kt < 8; ++kt) {
        const int kb = kt * 64;
        // stage: A 16KB (4 rounds), B (BR rounds); 128B rows, 8 slots of 16B
        #pragma unroll
        for (int i = 0; i < 4; ++i) {
            int f = i * 256 + t;
            int row = f >> 3;
            int sc  = (f & 7) ^ (row & 7);
            GLOAD_LDS16(A + (size_t)(r0 + row) * KA + kb + sc * 8, As + f * 8);
        }
        #pragma unroll
        for (int i = 0; i < BR; ++i) {
            int f = i * 256 + t;
            int row = f >> 3;
            int sc  = (f & 7) ^ (row & 7);
            GLOAD_LDS16(Wz + (size_t)(cw + row) * KA + kb + sc * 8, Bs + f * 8);
        }
        __syncthreads();   // drains vmcnt -> staged data visible

        #pragma unroll
        for (int kk = 0; kk < 2; ++kk) {
            f16x8 af[4], bfr[NW];
            #pragma unroll
            for (int mi = 0; mi < 4; ++mi) {
                int lr = wr * 64 + mi * 16 + l16;
                int sc = (kk * 4 + g16) ^ (lr & 7);
                af[mi] = *(const f16x8*)(As + lr * 64 + sc * 8);
            }
            #pragma unroll
            for (int ni = 0; ni < NW; ++ni) {
                int lr = wc * (BN / 2) + ni * 16 + l16;
                int sc = (kk * 4 + g16) ^ (lr & 7);
                bfr[ni] = *(const f16x8*)(Bs + lr * 64 + sc * 8);
            }
            #pragma unroll
            for (int mi = 0; mi < 4; ++mi)
                #pragma unroll
                for (int ni = 0; ni < NW; ++ni)
                    acc[mi][ni] = __builtin_amdgcn_mfma_f32_16x16x32_f16(af[mi], bfr[ni], acc[mi][ni], 0, 0, 0);
        }
        __syncthreads();   // protect LDS from next stage's overwrite
    }

    // ---- epilogue --------------------------------------------------------
    if (OUTMODE == 1) {
        #pragma unroll
        for (int mi = 0; mi < 4; ++mi)
            #pragma unroll
            for (int ni = 0; ni < NW; ++ni) {
                int cg = c0 + wc * (BN / 2) + ni * 16 + l16;
                float bv = b0[cg];
                #pragma unroll
                for (int r = 0; r < 4; ++r) {
                    int rg = r0 + wr * 64 + mi * 16 + g16 * 4 + r;
                    obase[(size_t)rg * DD + cg] = acc[mi][ni][r] + bv;
                }
            }
    } else {
        const float* bias = (z == 0) ? b0 : (z == 1) ? b1 : b2;
        float* outp = obase + (size_t)z * PLANE;

        #pragma unroll
        for (int mi = 0; mi < 4; ++mi)
            #pragma unroll
            for (int ni = 0; ni < NW; ++ni) {
                float bv = bias[cw + wc * 64 + ni * 16 + l16];
                #pragma unroll
                for (int r = 0; r < 4; ++r) {
                    float v = acc[mi][ni][r] + bv;
                    if (z < 2) v = (v > 0.f) ? v : expm1f(v);
                    acc[mi][ni][r] = v;
                }
            }
        if (z < 2) {
            // per-(row, head) L2 norm; wave's 64 cols == one head
            #pragma unroll
            for (int mi = 0; mi < 4; ++mi)
                #pragma unroll
                for (int r = 0; r < 4; ++r) {
                    float ss = 0.f;
                    #pragma unroll
                    for (int ni = 0; ni < NW; ++ni) ss += acc[mi][ni][r] * acc[mi][ni][r];
                    ss += __shfl_xor(ss, 1);
                    ss += __shfl_xor(ss, 2);
                    ss += __shfl_xor(ss, 4);
                    ss += __shfl_xor(ss, 8);
                    float sc = 1.f / fmaxf(sqrtf(ss), 1e-12f);
                    #pragma unroll
                    for (int ni = 0; ni < NW; ++ni) acc[mi][ni][r] *= sc;
                }
        }
        const int h = (cw >> 6) + wc;
        #pragma unroll
        for (int mi = 0; mi < 4; ++mi)
            #pragma unroll
            for (int r = 0; r < 4; ++r) {
                int rg = r0 + wr * 64 + mi * 16 + g16 * 4 + r;
                int b = rg >> 10, n = rg & 1023;
                float* dst = outp + ((size_t)(b * HH + h) * NN + n) * HDIM;
                #pragma unroll
                for (int ni = 0; ni < NW; ++ni) dst[ni * 16 + l16] = acc[mi][ni][r];
            }
    }
}

// ---------------------------------------------------------------------------
// Per-chunk state: S_c[d][e] = sum_{n in chunk} K[n][d] * V[n][e]   (64x64)
// ---------------------------------------------------------------------------
__global__ __launch_bounds__(256)
void chunk_state(const float* __restrict__ kb, const float* __restrict__ vb,
                 float* __restrict__ S)
{
    __shared__ float Ks[64 * 64];
    __shared__ float Vs[64 * 64];

    const int bh = blockIdx.x;
    const int ch = blockIdx.y;
    const int t  = threadIdx.x;

    const float4* kg4 = (const float4*)(kb + ((size_t)bh * NN + ch * 64) * HDIM);
    const float4* vg4 = (const float4*)(vb + ((size_t)bh * NN + ch * 64) * HDIM);

    #pragma unroll
    for (int i = 0; i < 4; ++i) {
        int f4 = t + i * 256;
        ((float4*)Ks)[f4] = kg4[f4];
        ((float4*)Vs)[f4] = vg4[f4];
    }
    __syncthreads();

    const int d0 = (t >> 4) * 4;
    const int e0 = (t & 15) * 4;
    f32x4 acc[4] = {};
    for (int n = 0; n < 64; ++n) {
        f32x4 kv = *(const f32x4*)(Ks + n * 64 + d0);
        f32x4 vv = *(const f32x4*)(Vs + n * 64 + e0);
        #pragma unroll
        for (int di = 0; di < 4; ++di) acc[di] += kv[di] * vv;
    }
    float* sg = S + ((size_t)bh * NCHUNK + ch) * 4096;
    #pragma unroll
    for (int di = 0; di < 4; ++di)
        *(f32x4*)(sg + (d0 + di) * 64 + e0) = acc[di];
}

// ---------------------------------------------------------------------------
// Chunk attention: O = Q @ P + tril(Q K^T) @ V -> fp16 rows for the out-proj.
// P (exclusive prefix of states) accumulated per-thread in registers.
// ---------------------------------------------------------------------------
__global__ __launch_bounds__(256)
void attn_chunk(const float* __restrict__ qb, const float* __restrict__ kb,
                const float* __restrict__ vb, const float* __restrict__ S,
                f16* __restrict__ aug)
{
    __shared__ float Qs[64][68];   // [i][d], rows 16B-aligned
    __shared__ float Kt[64][68];   // [d][j]
    __shared__ float PA[64 * 68];  // P [d*64+e] first, then scores [i*68+j]
    __shared__ float Vs[64 * 64];

    const int bh = blockIdx.x;
    const int ch = blockIdx.y;
    const int t  = threadIdx.x;

    const float4* qg4 = (const float4*)(qb + ((size_t)bh * NN + ch * 64) * HDIM);
    const float4* kg4 = (const float4*)(kb + ((size_t)bh * NN + ch * 64) * HDIM);
    const float4* vg4 = (const float4*)(vb + ((size_t)bh * NN + ch * 64) * HDIM);
    const float*  stb = S + (size_t)bh * NCHUNK * 4096;

    #pragma unroll
    for (int i = 0; i < 4; ++i) {
        int f4 = t + i * 256;
        int n  = f4 >> 4;
        int d4 = (f4 & 15) * 4;
        float4 q4 = qg4[f4];
        Qs[n][d4 + 0] = q4.x; Qs[n][d4 + 1] = q4.y; Qs[n][d4 + 2] = q4.z; Qs[n][d4 + 3] = q4.w;
        float4 k4 = kg4[f4];
        Kt[d4 + 0][n] = k4.x; Kt[d4 + 1][n] = k4.y; Kt[d4 + 2][n] = k4.z; Kt[d4 + 3][n] = k4.w;
        ((float4*)Vs)[f4] = vg4[f4];
    }

    // exclusive prefix of chunk states, accumulated in regs (L2-resident)
    f32x4 racc[4] = {};
    for (int c = 0; c < ch; ++c) {
        const f32x4* sg4 = (const f32x4*)(stb + (size_t)c * 4096);
        #pragma unroll
        for (int i = 0; i < 4; ++i) racc[i] += sg4[t + i * 256];
    }
    #pragma unroll
    for (int i = 0; i < 4; ++i) ((f32x4*)PA)[t + i * 256] = racc[i];
    __syncthreads();

    const int r  = (t >> 4) * 4;   // 4 output rows
    const int cN = (t & 15) * 4;   // 4 output cols

    // o = Q @ P
    f32x4 o[4] = {};
    for (int d4 = 0; d4 < 16; ++d4) {
        f32x4 q[4], p[4];
        #pragma unroll
        for (int ri = 0; ri < 4; ++ri) q[ri] = *(const f32x4*)&Qs[r + ri][d4 * 4];
        #pragma unroll
        for (int l = 0; l < 4; ++l) p[l] = *(const f32x4*)(PA + (d4 * 4 + l) * 64 + cN);
        #pragma unroll
        for (int ri = 0; ri < 4; ++ri)
            #pragma unroll
            for (int l = 0; l < 4; ++l) o[ri] += q[ri][l] * p[l];
    }

    // scores a = Q K^T (touches only Qs/Kt)
    f32x4 a[4] = {};
    for (int d4 = 0; d4 < 16; ++d4) {
        f32x4 q[4], kv[4];
        #pragma unroll
        for (int ri = 0; ri < 4; ++ri) q[ri] = *(const f32x4*)&Qs[r + ri][d4 * 4];
        #pragma unroll
        for (int l = 0; l < 4; ++l) kv[l] = *(const f32x4*)&Kt[d4 * 4 + l][cN];
        #pragma unroll
        for (int ri = 0; ri < 4; ++ri)
            #pragma unroll
            for (int l = 0; l < 4; ++l) a[ri] += q[ri][l] * kv[l];
    }
    __syncthreads();   // all P reads done -> safe to overlay

    #pragma unroll
    for (int ri = 0; ri < 4; ++ri)
        #pragma unroll
        for (int l = 0; l < 4; ++l) {
            int j = cN + l;
            PA[(r + ri) * 68 + j] = (j <= r + ri) ? a[ri][l] : 0.f;
        }
    __syncthreads();

    // o += A @ V
    for (int j4 = 0; j4 < 16; ++j4) {
        f32x4 av[4], v[4];
        #pragma unroll
        for (int ri = 0; ri < 4; ++ri) av[ri] = *(const f32x4*)(PA + (r + ri) * 68 + j4 * 4);
        #pragma unroll
        for (int l = 0; l < 4; ++l) v[l] = *(const f32x4*)(Vs + (j4 * 4 + l) * 64 + cN);
        #pragma unroll
        for (int ri = 0; ri < 4; ++ri)
            #pragma unroll
            for (int l = 0; l < 4; ++l) o[ri] += av[ri][l] * v[l];
    }

    // emit fp16 rows for the out-projection
    const int b = bh >> 3;
    const int h = bh & 7;
    #pragma unroll
    for (int ri = 0; ri < 4; ++ri) {
        const int rg = b * NN + ch * 64 + r + ri;
        f16x4 hv;
        #pragma unroll
        for (int l = 0; l < 4; ++l) hv[l] = (f16)o[ri][l];
        *(f16x4*)(aug + (size_t)rg * KA + h * HDIM + cN) = hv;
    }
}

// ---------------------------------------------------------------------------
extern "C" void kernel_launch(void* const* d_in, const int* in_sizes, int n_in,
                              void* d_out, int out_size, void* d_ws, size_t ws_size,
                              hipStream_t stream)
{
    (void)in_sizes; (void)n_in; (void)out_size; (void)ws_size;

    const float* x  = (const float*)d_in[0];
    const float* Wq = (const float*)d_in[1];
    const float* Wk = (const float*)d_in[2];
    const float* Wv = (const float*)d_in[3];
    const float* Wo = (const float*)d_in[4];
    const float* bq = (const float*)d_in[5];
    const float* bk = (const float*)d_in[6];
    const float* bv = (const float*)d_in[7];
    const float* bo = (const float*)d_in[8];
    float* out = (float*)d_out;

    // workspace: qb 8M | kb 8M | vb 8M | st 8M | xa 4M | aug 4M | wa 4M
    char* ws = (char*)d_ws;
    float* qb  = (float*)(ws);
    float* kb  = (float*)(ws + (size_t)8  * 1024 * 1024);
    float* vb  = (float*)(ws + (size_t)16 * 1024 * 1024);
    float* st  = (float*)(ws + (size_t)24 * 1024 * 1024);
    f16*   xa  = (f16*)  (ws + (size_t)32 * 1024 * 1024);
    f16*   aug = (f16*)  (ws + (size_t)36 * 1024 * 1024);
    f16*   wa  = (f16*)  (ws + (size_t)40 * 1024 * 1024);

    dim3 blk(256);

    split_all<<<dim3(3072), blk, 0, stream>>>(x, Wq, Wk, Wv, Wo, xa, wa);

    // fused q,k,v projections: N = 1536 (3 matrices x 512), K = 512
    mm_f16<0><<<dim3(32, 12), blk, 0, stream>>>(xa, wa, bq, bk, bv, qb);

    chunk_state<<<dim3(32, NCHUNK), blk, 0, stream>>>(kb, vb, st);
    attn_chunk<<<dim3(32, NCHUNK), blk, 0, stream>>>(qb, kb, vb, st, aug);

    // out projection: K = 512
    mm_f16<1><<<dim3(32, 8), blk, 0, stream>>>(aug, wa + (size_t)3 * WMAT, bo, nullptr, nullptr, out);
}

// Round 9
// 60.284 us; speedup vs baseline: 1.7063x; 1.2183x over previous
//
#include <hip/hip_runtime.h>
#include <cmath>

// Problem constants
#define BB 4
#define NN 1024
#define DD 512
#define HH 8
#define HDIM 64
#define ROWS (BB * NN)      // 4096
#define NCHUNK 16
#define KA 512
#define WMAT ((size_t)512 * 512)    // one fp16 weight matrix, elems

typedef _Float16 f16;
typedef f16   f16x8 __attribute__((ext_vector_type(8)));
typedef f16   f16x4 __attribute__((ext_vector_type(4)));
typedef float f32x4 __attribute__((ext_vector_type(4)));

#define GLOAD_LDS16(g, l) \
    __builtin_amdgcn_global_load_lds((const __attribute__((address_space(1))) void*)(g), \
                                     (__attribute__((address_space(3))) void*)(l), 16, 0, 0)

// ---------------------------------------------------------------------------
// Fused split: x -> fp16 rows; W -> fp16.
// ---------------------------------------------------------------------------
__global__ __launch_bounds__(256)
void split_all(const float* __restrict__ x,
               const float* __restrict__ Wq, const float* __restrict__ Wk,
               const float* __restrict__ Wv, const float* __restrict__ Wo,
               f16* __restrict__ xa, f16* __restrict__ wa)
{
    const int bid = blockIdx.x;
    const float* src;
    f16* dstbase;
    int t;
    if (bid < 2048) {                       // x: 2M floats
        t = bid * 256 + threadIdx.x;
        src = x;
        dstbase = xa;
    } else {                                // weights: 4 x 256K floats
        int wb = bid - 2048;
        int m  = wb >> 8;
        t = (wb & 255) * 256 + threadIdx.x;
        src = (m == 0) ? Wq : (m == 1) ? Wk : (m == 2) ? Wv : Wo;
        dstbase = wa + (size_t)m * WMAT;
    }
    float4 v = ((const float4*)src)[t];
    int r = t >> 7;
    int c = (t & 127) * 4;
    f16x4 h;
    h[0] = (f16)v.x; h[1] = (f16)v.y; h[2] = (f16)v.z; h[3] = (f16)v.w;
    *(f16x4*)(dstbase + (size_t)r * 512 + c) = h;
}

// ---------------------------------------------------------------------------
// fp16 MFMA GEMM (m97 structure; 128xBN tile, BK=64, XOR-8 swizzle, single
// buffer, 2-barrier loop). K = 512 -> 8 iters.
// OUTMODE 0: BN=128, grid (32,12): z = c0>>9 picks q/k/v.
//   z=0: elu+L2norm, store q fp16 [bh][n][d]
//   z=1: elu+L2norm, store k fp16 [bh][n][d] AND kT fp16 [bh][d][n] (LDS transpose)
//   z=2: bias only,  store vT fp16 [bh][e][n] (LDS transpose)
// OUTMODE 1: BN=64, grid (32,8): bias + row-major f32 store to out.
// ---------------------------------------------------------------------------
template<int OUTMODE>
__global__ __launch_bounds__(256)
void mm_f16(const f16* __restrict__ A, const f16* __restrict__ Wm,
            const float* __restrict__ b0, const float* __restrict__ b1,
            const float* __restrict__ b2,
            f16* __restrict__ qf, f16* __restrict__ kf,
            f16* __restrict__ ktb, f16* __restrict__ vtb,
            float* __restrict__ obase)
{
    constexpr int BN = (OUTMODE == 0) ? 128 : 64;
    constexpr int NW = BN / 32;
    constexpr int BR = BN / 32;

    __shared__ __align__(16) f16 As[128 * 64];   // 16KB
    __shared__ __align__(16) f16 Bs[BN * 64];    // 16KB or 8KB

    const int t    = threadIdx.x;
    const int lane = t & 63;
    const int wid  = t >> 6;
    const int wr   = wid >> 1;
    const int wc   = wid & 1;
    const int l16  = lane & 15;
    const int g16  = lane >> 4;

    // bijective XCD swizzle over the linearized grid
    const int nwg = 32 * gridDim.y;
    const int lin = blockIdx.y * 32 + blockIdx.x;
    const int swz = (lin & 7) * (nwg >> 3) + (lin >> 3);
    const int bx  = swz & 31;
    const int by  = swz >> 5;

    const int r0 = bx * 128;
    const int c0 = by * BN;
    const int z  = (OUTMODE == 0) ? (c0 >> 9) : 0;
    const int cw = (OUTMODE == 0) ? (c0 & 511) : c0;

    const f16* Wz = Wm + (size_t)z * WMAT;

    f32x4 acc[4][NW] = {};

    for (int kt = 0; kt < 8; ++kt) {
        const int kb = kt * 64;
        #pragma unroll
        for (int i = 0; i < 4; ++i) {
            int f = i * 256 + t;
            int row = f >> 3;
            int sc  = (f & 7) ^ (row & 7);
            GLOAD_LDS16(A + (size_t)(r0 + row) * KA + kb + sc * 8, As + f * 8);
        }
        #pragma unroll
        for (int i = 0; i < BR; ++i) {
            int f = i * 256 + t;
            int row = f >> 3;
            int sc  = (f & 7) ^ (row & 7);
            GLOAD_LDS16(Wz + (size_t)(cw + row) * KA + kb + sc * 8, Bs + f * 8);
        }
        __syncthreads();

        #pragma unroll
        for (int kk = 0; kk < 2; ++kk) {
            f16x8 af[4], bfr[NW];
            #pragma unroll
            for (int mi = 0; mi < 4; ++mi) {
                int lr = wr * 64 + mi * 16 + l16;
                int sc = (kk * 4 + g16) ^ (lr & 7);
                af[mi] = *(const f16x8*)(As + lr * 64 + sc * 8);
            }
            #pragma unroll
            for (int ni = 0; ni < NW; ++ni) {
                int lr = wc * (BN / 2) + ni * 16 + l16;
                int sc = (kk * 4 + g16) ^ (lr & 7);
                bfr[ni] = *(const f16x8*)(Bs + lr * 64 + sc * 8);
            }
            #pragma unroll
            for (int mi = 0; mi < 4; ++mi)
                #pragma unroll
                for (int ni = 0; ni < NW; ++ni)
                    acc[mi][ni] = __builtin_amdgcn_mfma_f32_16x16x32_f16(af[mi], bfr[ni], acc[mi][ni], 0, 0, 0);
        }
        __syncthreads();
    }

    // ---- epilogue --------------------------------------------------------
    if (OUTMODE == 1) {
        #pragma unroll
        for (int mi = 0; mi < 4; ++mi)
            #pragma unroll
            for (int ni = 0; ni < NW; ++ni) {
                int cg = c0 + wc * (BN / 2) + ni * 16 + l16;
                float bv = b0[cg];
                #pragma unroll
                for (int r = 0; r < 4; ++r) {
                    int rg = r0 + wr * 64 + mi * 16 + g16 * 4 + r;
                    obase[(size_t)rg * DD + cg] = acc[mi][ni][r] + bv;
                }
            }
    } else {
        const float* bias = (z == 0) ? b0 : (z == 1) ? b1 : b2;

        // bias (+ elu for q,k)
        #pragma unroll
        for (int mi = 0; mi < 4; ++mi)
            #pragma unroll
            for (int ni = 0; ni < NW; ++ni) {
                float bv = bias[cw + wc * 64 + ni * 16 + l16];
                #pragma unroll
                for (int r = 0; r < 4; ++r) {
                    float v = acc[mi][ni][r] + bv;
                    if (z < 2) v = (v > 0.f) ? v : expm1f(v);
                    acc[mi][ni][r] = v;
                }
            }
        if (z < 2) {
            // per-(row, head) L2 norm; wave's 64 cols == one head
            #pragma unroll
            for (int mi = 0; mi < 4; ++mi)
                #pragma unroll
                for (int r = 0; r < 4; ++r) {
                    float ss = 0.f;
                    #pragma unroll
                    for (int ni = 0; ni < NW; ++ni) ss += acc[mi][ni][r] * acc[mi][ni][r];
                    ss += __shfl_xor(ss, 1);
                    ss += __shfl_xor(ss, 2);
                    ss += __shfl_xor(ss, 4);
                    ss += __shfl_xor(ss, 8);
                    float sc = 1.f / fmaxf(sqrtf(ss), 1e-12f);
                    #pragma unroll
                    for (int ni = 0; ni < NW; ++ni) acc[mi][ni][r] *= sc;
                }
        }

        const int h = (cw >> 6) + wc;        // head of this wave's 64 cols
        const int b = r0 >> 10;              // all 128 rows same batch

        // direct fp16 [bh][n][d] store for q,k
        if (z <= 1) {
            f16* plane = (z == 0) ? qf : kf;
            #pragma unroll
            for (int mi = 0; mi < 4; ++mi)
                #pragma unroll
                for (int r = 0; r < 4; ++r) {
                    int rg = r0 + wr * 64 + mi * 16 + g16 * 4 + r;
                    f16* dst = plane + ((size_t)(b * HH + h) * NN + (rg & 1023)) * HDIM;
                    #pragma unroll
                    for (int ni = 0; ni < NW; ++ni) dst[ni * 16 + l16] = (f16)acc[mi][ni][r];
                }
        }

        // transposed fp16 [bh][d][n] store for k,v via per-wave LDS transpose
        if (z >= 1) {
            f16* tb = (z == 1) ? ktb : vtb;
            f16* T = (wid < 2) ? (As + wid * 4096) : (Bs + (wid - 2) * 4096);
            // write acc into T[d][n] (rows 64 f16 = 128B, XOR-8 swizzled)
            #pragma unroll
            for (int mi = 0; mi < 4; ++mi)
                #pragma unroll
                for (int ni = 0; ni < NW; ++ni)
                    #pragma unroll
                    for (int r = 0; r < 4; ++r) {
                        int n_ = mi * 16 + g16 * 4 + r;      // wave-local row
                        int d_ = ni * 16 + l16;              // wave-local col
                        *(f16*)((char*)T + d_ * 128 + (((n_ >> 3) ^ (d_ & 7)) * 16) + (n_ & 7) * 2)
                            = (f16)acc[mi][ni][r];
                    }
            __syncthreads();
            // read rows of T (d-major) and store coalesced: 8 passes
            const int n0 = (r0 & 1023) + wr * 64;
            #pragma unroll
            for (int p = 0; p < 8; ++p) {
                int d_ = p * 8 + (lane >> 3);
                int ck = lane & 7;
                f16x8 v8 = *(const f16x8*)((char*)T + d_ * 128 + ((ck ^ (d_ & 7)) * 16));
                *(f16x8*)(tb + ((size_t)(b * HH + h) * HDIM + d_) * NN + n0 + ck * 8) = v8;
            }
        }
    }
}

// ---------------------------------------------------------------------------
// Per-chunk state via MFMA: ST[e][d] = sum_n vT[e][n] * kT[d][n]  (fp32 out)
// ---------------------------------------------------------------------------
__global__ __launch_bounds__(256)
void chunk_state(const f16* __restrict__ ktb, const f16* __restrict__ vtb,
                 float* __restrict__ S)
{
    __shared__ __align__(16) f16 Kt[64 * 64];   // 8KB, swizzled
    __shared__ __align__(16) f16 Vt[64 * 64];

    const int bh = blockIdx.x;
    const int ch = blockIdx.y;
    const int t  = threadIdx.x;
    const int lane = t & 63;
    const int wid  = t >> 6;
    const int wr   = wid >> 1;
    const int wc   = wid & 1;
    const int l16  = lane & 15;
    const int g16  = lane >> 4;

    #pragma unroll
    for (int i = 0; i < 2; ++i) {
        int f = i * 256 + t;
        int row = f >> 3;
        int sc  = (f & 7) ^ (row & 7);
        GLOAD_LDS16(ktb + ((size_t)bh * HDIM + row) * NN + ch * 64 + sc * 8, Kt + f * 8);
        GLOAD_LDS16(vtb + ((size_t)bh * HDIM + row) * NN + ch * 64 + sc * 8, Vt + f * 8);
    }
    __syncthreads();

    f32x4 acc[2][2] = {};
    #pragma unroll
    for (int ks = 0; ks < 2; ++ks) {
        f16x8 af[2], bfr[2];
        #pragma unroll
        for (int mi = 0; mi < 2; ++mi) {
            int row = wr * 32 + mi * 16 + l16;              // e
            int sc  = (ks * 4 + g16) ^ (row & 7);
            af[mi] = *(const f16x8*)(Vt + row * 64 + sc * 8);
        }
        #pragma unroll
        for (int ni = 0; ni < 2; ++ni) {
            int row = wc * 32 + ni * 16 + l16;              // d
            int sc  = (ks * 4 + g16) ^ (row & 7);
            bfr[ni] = *(const f16x8*)(Kt + row * 64 + sc * 8);
        }
        #pragma unroll
        for (int mi = 0; mi < 2; ++mi)
            #pragma unroll
            for (int ni = 0; ni < 2; ++ni)
                acc[mi][ni] = __builtin_amdgcn_mfma_f32_16x16x32_f16(af[mi], bfr[ni], acc[mi][ni], 0, 0, 0);
    }

    float* sg = S + ((size_t)bh * NCHUNK + ch) * 4096;
    #pragma unroll
    for (int mi = 0; mi < 2; ++mi)
        #pragma unroll
        for (int ni = 0; ni < 2; ++ni)
            #pragma unroll
            for (int r = 0; r < 4; ++r) {
                int e = wr * 32 + mi * 16 + g16 * 4 + r;
                int d = wc * 32 + ni * 16 + l16;
                sg[e * 64 + d] = acc[mi][ni][r];
            }
}

// ---------------------------------------------------------------------------
// Chunk attention via MFMA: scores = tril(Q K^T); O = Q P^T + scores V^T.
// P^T = fp32 prefix of ST, converted fp16 in LDS.  -> aug fp16 [rg][h*64+e]
// ---------------------------------------------------------------------------
__global__ __launch_bounds__(256)
void attn_chunk(const f16* __restrict__ qf, const f16* __restrict__ kf,
                const f16* __restrict__ vtb, const float* __restrict__ S,
                f16* __restrict__ aug)
{
    __shared__ __align__(16) f16 Qs[64 * 64];   // 8KB each, swizzled rows
    __shared__ __align__(16) f16 Ks[64 * 64];
    __shared__ __align__(16) f16 Vt[64 * 64];
    __shared__ __align__(16) f16 Pt[64 * 64];
    __shared__ __align__(16) f16 Ss[64 * 64];

    const int bh = blockIdx.x;
    const int ch = blockIdx.y;
    const int t  = threadIdx.x;
    const int lane = t & 63;
    const int wid  = t >> 6;
    const int wr   = wid >> 1;
    const int wc   = wid & 1;
    const int l16  = lane & 15;
    const int g16  = lane >> 4;

    // stage q, k (rows n), vT (rows e)
    #pragma unroll
    for (int i = 0; i < 2; ++i) {
        int f = i * 256 + t;
        int row = f >> 3;
        int sc  = (f & 7) ^ (row & 7);
        GLOAD_LDS16(qf  + ((size_t)bh * NN + ch * 64 + row) * HDIM + sc * 8, Qs + f * 8);
        GLOAD_LDS16(kf  + ((size_t)bh * NN + ch * 64 + row) * HDIM + sc * 8, Ks + f * 8);
        GLOAD_LDS16(vtb + ((size_t)bh * HDIM + row) * NN + ch * 64 + sc * 8, Vt + f * 8);
    }

    // exclusive prefix of ST in regs -> fp16 Pt[e][d]
    {
        f32x4 r4[4] = {};
        const float* stb = S + (size_t)bh * NCHUNK * 4096;
        for (int c = 0; c < ch; ++c) {
            const f32x4* p = (const f32x4*)(stb + (size_t)c * 4096 + t * 16);
            #pragma unroll
            for (int j = 0; j < 4; ++j) r4[j] += p[j];
        }
        const int e  = t >> 2;
        const int d0 = (t & 3) * 16;
        f16x8 h0, h1;
        #pragma unroll
        for (int j = 0; j < 8; ++j) { h0[j] = (f16)r4[j >> 2][j & 3]; h1[j] = (f16)r4[2 + (j >> 2)][j & 3]; }
        int s0 = (d0 >> 3);
        *(f16x8*)((char*)Pt + e * 128 + ((s0 ^ (e & 7)) * 16))       = h0;
        *(f16x8*)((char*)Pt + e * 128 + (((s0 + 1) ^ (e & 7)) * 16)) = h1;
    }
    __syncthreads();

    // scores = Q K^T (A=q rows i, B=k rows j), mask, -> Ss fp16
    f32x4 sacc[2][2] = {};
    #pragma unroll
    for (int ks = 0; ks < 2; ++ks) {
        f16x8 af[2], bfr[2];
        #pragma unroll
        for (int mi = 0; mi < 2; ++mi) {
            int row = wr * 32 + mi * 16 + l16;
            int sc  = (ks * 4 + g16) ^ (row & 7);
            af[mi] = *(const f16x8*)(Qs + row * 64 + sc * 8);
        }
        #pragma unroll
        for (int ni = 0; ni < 2; ++ni) {
            int row = wc * 32 + ni * 16 + l16;
            int sc  = (ks * 4 + g16) ^ (row & 7);
            bfr[ni] = *(const f16x8*)(Ks + row * 64 + sc * 8);
        }
        #pragma unroll
        for (int mi = 0; mi < 2; ++mi)
            #pragma unroll
            for (int ni = 0; ni < 2; ++ni)
                sacc[mi][ni] = __builtin_amdgcn_mfma_f32_16x16x32_f16(af[mi], bfr[ni], sacc[mi][ni], 0, 0, 0);
    }
    #pragma unroll
    for (int mi = 0; mi < 2; ++mi)
        #pragma unroll
        for (int ni = 0; ni < 2; ++ni)
            #pragma unroll
            for (int r = 0; r < 4; ++r) {
                int i = wr * 32 + mi * 16 + g16 * 4 + r;
                int j = wc * 32 + ni * 16 + l16;
                float v = (j <= i) ? sacc[mi][ni][r] : 0.f;
                *(f16*)((char*)Ss + i * 128 + (((j >> 3) ^ (i & 7)) * 16) + (j & 7) * 2) = (f16)v;
            }
    __syncthreads();

    // O = Q P^T + S V^T
    f32x4 oacc[2][2] = {};
    #pragma unroll
    for (int ks = 0; ks < 2; ++ks) {
        f16x8 af[2], bfr[2];
        #pragma unroll
        for (int mi = 0; mi < 2; ++mi) {
            int row = wr * 32 + mi * 16 + l16;
            int sc  = (ks * 4 + g16) ^ (row & 7);
            af[mi] = *(const f16x8*)(Qs + row * 64 + sc * 8);
        }
        #pragma unroll
        for (int ni = 0; ni < 2; ++ni) {
            int row = wc * 32 + ni * 16 + l16;          // e
            int sc  = (ks * 4 + g16) ^ (row & 7);
            bfr[ni] = *(const f16x8*)(Pt + row * 64 + sc * 8);
        }
        #pragma unroll
        for (int mi = 0; mi < 2; ++mi)
            #pragma unroll
            for (int ni = 0; ni < 2; ++ni)
                oacc[mi][ni] = __builtin_amdgcn_mfma_f32_16x16x32_f16(af[mi], bfr[ni], oacc[mi][ni], 0, 0, 0);
    }
    #pragma unroll
    for (int ks = 0; ks < 2; ++ks) {
        f16x8 af[2], bfr[2];
        #pragma unroll
        for (int mi = 0; mi < 2; ++mi) {
            int row = wr * 32 + mi * 16 + l16;          // i
            int sc  = (ks * 4 + g16) ^ (row & 7);
            af[mi] = *(const f16x8*)(Ss + row * 64 + sc * 8);
        }
        #pragma unroll
        for (int ni = 0; ni < 2; ++ni) {
            int row = wc * 32 + ni * 16 + l16;          // e
            int sc  = (ks * 4 + g16) ^ (row & 7);
            bfr[ni] = *(const f16x8*)(Vt + row * 64 + sc * 8);
        }
        #pragma unroll
        for (int mi = 0; mi < 2; ++mi)
            #pragma unroll
            for (int ni = 0; ni < 2; ++ni)
                oacc[mi][ni] = __builtin_amdgcn_mfma_f32_16x16x32_f16(af[mi], bfr[ni], oacc[mi][ni], 0, 0, 0);
    }

    // emit fp16 rows for the out-projection
    const int b = bh >> 3;
    const int h = bh & 7;
    #pragma unroll
    for (int mi = 0; mi < 2; ++mi)
        #pragma unroll
        for (int ni = 0; ni < 2; ++ni)
            #pragma unroll
            for (int r = 0; r < 4; ++r) {
                int i = wr * 32 + mi * 16 + g16 * 4 + r;
                int e = wc * 32 + ni * 16 + l16;
                aug[((size_t)(b * NN + ch * 64 + i)) * KA + h * HDIM + e] = (f16)oacc[mi][ni][r];
            }
}

// ---------------------------------------------------------------------------
extern "C" void kernel_launch(void* const* d_in, const int* in_sizes, int n_in,
                              void* d_out, int out_size, void* d_ws, size_t ws_size,
                              hipStream_t stream)
{
    (void)in_sizes; (void)n_in; (void)out_size; (void)ws_size;

    const float* x  = (const float*)d_in[0];
    const float* Wq = (const float*)d_in[1];
    const float* Wk = (const float*)d_in[2];
    const float* Wv = (const float*)d_in[3];
    const float* Wo = (const float*)d_in[4];
    const float* bq = (const float*)d_in[5];
    const float* bk = (const float*)d_in[6];
    const float* bv = (const float*)d_in[7];
    const float* bo = (const float*)d_in[8];
    float* out = (float*)d_out;

    // ws: qf 4M | kf 4M | ktb 4M | vtb 4M | st 8M | xa 4M | aug 4M | wa 2M
    char* ws = (char*)d_ws;
    f16*   qf  = (f16*)  (ws);
    f16*   kf  = (f16*)  (ws + (size_t)4  * 1024 * 1024);
    f16*   ktb = (f16*)  (ws + (size_t)8  * 1024 * 1024);
    f16*   vtb = (f16*)  (ws + (size_t)12 * 1024 * 1024);
    float* st  = (float*)(ws + (size_t)16 * 1024 * 1024);
    f16*   xa  = (f16*)  (ws + (size_t)24 * 1024 * 1024);
    f16*   aug = (f16*)  (ws + (size_t)28 * 1024 * 1024);
    f16*   wa  = (f16*)  (ws + (size_t)32 * 1024 * 1024);

    dim3 blk(256);

    split_all<<<dim3(3072), blk, 0, stream>>>(x, Wq, Wk, Wv, Wo, xa, wa);

    // fused q,k,v projections: N = 1536 (3 matrices x 512), K = 512
    mm_f16<0><<<dim3(32, 12), blk, 0, stream>>>(xa, wa, bq, bk, bv, qf, kf, ktb, vtb, nullptr);

    chunk_state<<<dim3(32, NCHUNK), blk, 0, stream>>>(ktb, vtb, st);
    attn_chunk<<<dim3(32, NCHUNK), blk, 0, stream>>>(qf, kf, vtb, st, aug);

    // out projection: K = 512
    mm_f16<1><<<dim3(32, 8), blk, 0, stream>>>(aug, wa + (size_t)3 * WMAT, bo, nullptr, nullptr,
                                               nullptr, nullptr, nullptr, nullptr, out);
}